// Round 3
// baseline (4993.980 us; speedup 1.0000x reference)
//
#include <hip/hip_runtime.h>
#include <hip/hip_bf16.h>
#include <cstdint>
#include <cstddef>

// ---------------- problem constants ----------------
#define NB   2
#define CINC 768
#define PP   1936          // 44*44
#define CO   384
#define NHD  4
#define DH   192
#define FCH  1920          // 768 + 3*384

// ---------------- workspace layout (floats) ----------------
// Fixed region, then a sim slab whose bh-group size g is chosen from ws_size.
static const size_t OFF_CONV = 0;
static const size_t N_CONV   = (size_t)3 * NB * CO * PP;       // 4,460,544
static const size_t OFF_Q    = OFF_CONV + N_CONV;
static const size_t N_QKV    = (size_t)NB * NHD * PP * DH;     // 2,973,696
static const size_t OFF_K    = OFF_Q + N_QKV;
static const size_t OFF_V    = OFF_K + N_QKV;                  // channel-major [b][768][1936]
static const size_t OFF_O    = OFF_V + N_QKV;                  // channel-major [b][768][1936]
static const size_t OFF_QRH  = OFF_O + N_QKV;
static const size_t N_QR     = (size_t)NB * NHD * PP * 44;     // 681,472
static const size_t OFF_QRW  = OFF_QRH + N_QR;
static const size_t OFF_RS   = OFF_QRW + N_QR;                 // 15,488 rowsums
static const size_t OFF_SIM  = OFF_RS + (size_t)NB * NHD * PP; // slab: g*PP*PP
static const size_t SIM_BH   = (size_t)PP * PP;                // 3,748,096 per bh

// rank-1 outer-product accumulate: ACC[r][c] += A[r]*B[c]
#define FMAQ(ACC, A, B) { \
  ACC[0][0]+=A.x*B.x; ACC[0][1]+=A.x*B.y; ACC[0][2]+=A.x*B.z; ACC[0][3]+=A.x*B.w; \
  ACC[1][0]+=A.y*B.x; ACC[1][1]+=A.y*B.y; ACC[1][2]+=A.y*B.z; ACC[1][3]+=A.y*B.w; \
  ACC[2][0]+=A.z*B.x; ACC[2][1]+=A.z*B.y; ACC[2][2]+=A.z*B.z; ACC[2][3]+=A.z*B.w; \
  ACC[3][0]+=A.w*B.x; ACC[3][1]+=A.w*B.y; ACC[3][2]+=A.w*B.z; ACC[3][3]+=A.w*B.w; }

// ======================================================================
// K1: three dilated 3x3 convs (768 -> 384 each), zero-padded, + bias.
// 128 co x 8x8 spatial per block; thread = 8co(2 quadrants) x 4px.
// Templated on dilation so staging indexing uses compile-time divisors.
// ======================================================================
template<int DIL>
__device__ __forceinline__ void conv_body(
    float* xs, float* wsh,
    const float* __restrict__ xb, const float* __restrict__ w,
    const float* __restrict__ bia, float* __restrict__ outbase,
    int ty0, int tx0, int co0)
{
  constexpr int EXT = 8 + 2 * DIL;          // 14 / 18 / 22
  constexpr int EE  = EXT * EXT;
  const int tid = threadIdx.x;
  const int co_sub = (tid & 15) * 4;
  const int ps = (tid >> 4) * 4;
  const int py = ps >> 3, px0 = ps & 7;

  float acc[2][4][4];
  #pragma unroll
  for (int q = 0; q < 2; ++q)
    #pragma unroll
    for (int a = 0; a < 4; ++a)
      #pragma unroll
      for (int p = 0; p < 4; ++p) acc[q][a][p] = 0.f;

  for (int ci0 = 0; ci0 < CINC; ci0 += 4) {
    __syncthreads();
    for (int e = tid; e < 4 * EE; e += 256) {
      int ci = e / EE, r = e - ci * EE;
      int row = r / EXT, col = r - row * EXT;
      int gy = ty0 - DIL + row, gx = tx0 - DIL + col;
      float v = 0.f;
      if ((unsigned)gy < 44u && (unsigned)gx < 44u)
        v = xb[(size_t)(ci0 + ci) * PP + gy * 44 + gx];
      xs[ci * EE + r] = v;
    }
    #pragma unroll
    for (int h = 0; h < 18; ++h) {          // 4608 = 18*256 weights
      int e = tid + h * 256;
      int co = e & 127, r = e >> 7;          // r = ci*9+tap
      wsh[r * 128 + co] = w[(size_t)(co0 + co) * (CINC * 9) + ci0 * 9 + r];
    }
    __syncthreads();
    #pragma unroll
    for (int ci = 0; ci < 4; ++ci) {
      const float* xc = xs + ci * EE;
      #pragma unroll
      for (int kh = 0; kh < 3; ++kh) {
        const float* xr = xc + (py + DIL * kh) * EXT + px0;
        #pragma unroll
        for (int kw = 0; kw < 3; ++kw) {
          const float* xq = xr + DIL * kw;
          float4 xv = make_float4(xq[0], xq[1], xq[2], xq[3]);
          const float4 w0 = *(const float4*)&wsh[(ci * 9 + kh * 3 + kw) * 128 + co_sub];
          const float4 w1 = *(const float4*)&wsh[(ci * 9 + kh * 3 + kw) * 128 + co_sub + 64];
          FMAQ(acc[0], w0, xv)
          FMAQ(acc[1], w1, xv)
        }
      }
    }
  }
  const int gy = ty0 + py;
  #pragma unroll
  for (int q = 0; q < 2; ++q)
    #pragma unroll
    for (int a = 0; a < 4; ++a) {
      const int co = co0 + co_sub + q * 64 + a;
      const float bv = bia[co];
      float* dst = outbase + (size_t)co * PP;
      #pragma unroll
      for (int p = 0; p < 4; ++p) {
        int gx = tx0 + px0 + p;
        if (gy < 44 && gx < 44) dst[gy * 44 + gx] = acc[q][a][p] + bv;
      }
    }
}

__global__ __launch_bounds__(256) void k_conv(
    const float* __restrict__ x,
    const float* __restrict__ w3, const float* __restrict__ b3,
    const float* __restrict__ w5, const float* __restrict__ b5,
    const float* __restrict__ w7, const float* __restrict__ b7,
    float* __restrict__ conv_out)
{
  __shared__ alignas(16) float xs[4 * 484];
  __shared__ alignas(16) float wsh[4 * 9 * 128];
  const int zt = blockIdx.z, di = zt >> 1, b = zt & 1;
  const int pt = blockIdx.x;
  const int ty0 = (pt / 6) * 8, tx0 = (pt % 6) * 8;
  const int co0 = blockIdx.y * 128;
  const float* xb = x + (size_t)b * CINC * PP;
  float* outbase = conv_out + (size_t)(di * NB + b) * CO * PP;
  if (di == 0)      conv_body<3>(xs, wsh, xb, w3, b3, outbase, ty0, tx0, co0);
  else if (di == 1) conv_body<5>(xs, wsh, xb, w5, b5, outbase, ty0, tx0, co0);
  else              conv_body<7>(xs, wsh, xb, w7, b7, outbase, ty0, tx0, co0);
}

// ======================================================================
// K2: qk projection, 128o x 128p tile, 8x8 micro (2x2 quadrants).
// Writes q (scaled 0.5) and k in head layout [bh][pos][192].
// ======================================================================
__global__ __launch_bounds__(256) void k_qk(
    const float* __restrict__ x, const float* __restrict__ conv,
    const float* __restrict__ wqk,
    float* __restrict__ qbuf, float* __restrict__ kbuf)
{
  const int b = blockIdx.z;
  const int o0 = blockIdx.y * 128, p0 = blockIdx.x * 128;
  __shared__ alignas(16) float als[8 * 132];
  __shared__ alignas(16) float bls[8 * 132];
  const int tid = threadIdx.x;
  const int os4 = (tid & 15) * 4, ps4 = (tid >> 4) * 4;
  float acc[2][2][4][4];
  #pragma unroll
  for (int i = 0; i < 2; ++i)
    #pragma unroll
    for (int j = 0; j < 2; ++j)
      #pragma unroll
      for (int a = 0; a < 4; ++a)
        #pragma unroll
        for (int p = 0; p < 4; ++p) acc[i][j][a][p] = 0.f;

  const int aoo = tid >> 1, add = (tid & 1) * 4;
  const int bcc = tid >> 5;
  const int bp  = p0 + (tid & 31) * 4;
  const float* aptr = wqk + (size_t)(o0 + aoo) * FCH + add;

  for (int k0 = 0; k0 < FCH; k0 += 8) {
    float4 av = *(const float4*)(aptr + k0);
    float4 bv = make_float4(0.f, 0.f, 0.f, 0.f);
    {
      int c = k0 + bcc;
      if (bp < PP) {
        const float* src;
        if (c < CINC) src = x + ((size_t)b * CINC + c) * PP;
        else {
          int c2 = c - CINC; int dd2 = c2 / CO, cc2 = c2 - dd2 * CO;
          src = conv + ((size_t)(dd2 * NB + b) * CO + cc2) * PP;
        }
        bv = *(const float4*)(src + bp);
      }
    }
    __syncthreads();
    als[(add + 0) * 132 + aoo] = av.x;
    als[(add + 1) * 132 + aoo] = av.y;
    als[(add + 2) * 132 + aoo] = av.z;
    als[(add + 3) * 132 + aoo] = av.w;
    *(float4*)&bls[bcc * 132 + (tid & 31) * 4] = bv;
    __syncthreads();
    #pragma unroll
    for (int kk = 0; kk < 8; ++kk) {
      const float4 a0 = *(const float4*)&als[kk * 132 + os4];
      const float4 a1 = *(const float4*)&als[kk * 132 + os4 + 64];
      const float4 b0 = *(const float4*)&bls[kk * 132 + ps4];
      const float4 b1 = *(const float4*)&bls[kk * 132 + ps4 + 64];
      FMAQ(acc[0][0], a0, b0) FMAQ(acc[0][1], a0, b1)
      FMAQ(acc[1][0], a1, b0) FMAQ(acc[1][1], a1, b1)
    }
  }
  #pragma unroll
  for (int oq = 0; oq < 2; ++oq)
    #pragma unroll
    for (int a = 0; a < 4; ++a) {
      const int o = o0 + os4 + oq * 64 + a;
      const bool isq = (o < CINC);
      const int oo = isq ? o : o - CINC;
      const int hd = oo / DH, dd = oo - hd * DH;
      float* dst = (isq ? qbuf : kbuf) + ((size_t)(b * NHD + hd) * PP) * DH + dd;
      const float s = isq ? 0.5f : 1.0f;      // HEAD^-0.5 = 0.5
      #pragma unroll
      for (int pq = 0; pq < 2; ++pq)
        #pragma unroll
        for (int pi = 0; pi < 4; ++pi) {
          int pp = p0 + ps4 + pq * 64 + pi;
          if (pp < PP) dst[(size_t)pp * DH] = acc[oq][pq][a][pi] * s;
        }
    }
}

// ======================================================================
// K3: rel-pos dot products (uses scaled q, matching reference).
// ======================================================================
__global__ __launch_bounds__(128) void k_qrel(
    const float* __restrict__ qbuf, const float* __restrict__ relh,
    const float* __restrict__ relw,
    float* __restrict__ qrh, float* __restrict__ qrw)
{
  const int bh = blockIdx.x / PP, pos = blockIdx.x % PP;
  const int xr = pos / 44, yc = pos - 44 * xr;
  __shared__ alignas(16) float qs[192];
  const int tid = threadIdx.x;
  for (int e = tid; e < 192; e += 128)
    qs[e] = qbuf[((size_t)bh * PP + pos) * DH + e];
  __syncthreads();
  const float4* q4 = (const float4*)qs;
  if (tid < 44) {
    const float4* r4 = (const float4*)&relh[(size_t)(tid - xr + 99) * DH];
    float s = 0.f;
    #pragma unroll
    for (int d = 0; d < 48; ++d) {
      float4 a = q4[d], bb = r4[d];
      s += a.x * bb.x + a.y * bb.y + a.z * bb.z + a.w * bb.w;
    }
    qrh[((size_t)bh * PP + pos) * 44 + tid] = s;
  } else if (tid >= 64 && tid < 108) {
    const int v = tid - 64;
    const float4* r4 = (const float4*)&relw[(size_t)(v - yc + 99) * DH];
    float s = 0.f;
    #pragma unroll
    for (int d = 0; d < 48; ++d) {
      float4 a = q4[d], bb = r4[d];
      s += a.x * bb.x + a.y * bb.y + a.z * bb.z + a.w * bb.w;
    }
    qrw[((size_t)bh * PP + pos) * 44 + v] = s;
  }
}

// ======================================================================
// K4: v projection -> channel-major vchan[b][768][1936].
// ======================================================================
__global__ __launch_bounds__(256) void k_v(
    const float* __restrict__ x, const float* __restrict__ wv,
    float* __restrict__ vchan)
{
  const int b = blockIdx.z;
  const int o0 = blockIdx.y * 128, p0 = blockIdx.x * 128;
  __shared__ alignas(16) float als[8 * 132];
  __shared__ alignas(16) float bls[8 * 132];
  const int tid = threadIdx.x;
  const int os4 = (tid & 15) * 4, ps4 = (tid >> 4) * 4;
  float acc[2][2][4][4];
  #pragma unroll
  for (int i = 0; i < 2; ++i)
    #pragma unroll
    for (int j = 0; j < 2; ++j)
      #pragma unroll
      for (int a = 0; a < 4; ++a)
        #pragma unroll
        for (int p = 0; p < 4; ++p) acc[i][j][a][p] = 0.f;

  const int aoo = tid >> 1, add = (tid & 1) * 4;
  const int bcc = tid >> 5;
  const int bp  = p0 + (tid & 31) * 4;
  const float* aptr = wv + (size_t)(o0 + aoo) * CINC + add;

  for (int k0 = 0; k0 < CINC; k0 += 8) {
    float4 av = *(const float4*)(aptr + k0);
    float4 bv = (bp < PP)
        ? *(const float4*)&x[((size_t)b * CINC + k0 + bcc) * PP + bp]
        : make_float4(0.f, 0.f, 0.f, 0.f);
    __syncthreads();
    als[(add + 0) * 132 + aoo] = av.x;
    als[(add + 1) * 132 + aoo] = av.y;
    als[(add + 2) * 132 + aoo] = av.z;
    als[(add + 3) * 132 + aoo] = av.w;
    *(float4*)&bls[bcc * 132 + (tid & 31) * 4] = bv;
    __syncthreads();
    #pragma unroll
    for (int kk = 0; kk < 8; ++kk) {
      const float4 a0 = *(const float4*)&als[kk * 132 + os4];
      const float4 a1 = *(const float4*)&als[kk * 132 + os4 + 64];
      const float4 b0 = *(const float4*)&bls[kk * 132 + ps4];
      const float4 b1 = *(const float4*)&bls[kk * 132 + ps4 + 64];
      FMAQ(acc[0][0], a0, b0) FMAQ(acc[0][1], a0, b1)
      FMAQ(acc[1][0], a1, b0) FMAQ(acc[1][1], a1, b1)
    }
  }
  #pragma unroll
  for (int oq = 0; oq < 2; ++oq)
    #pragma unroll
    for (int a = 0; a < 4; ++a) {
      const int o = o0 + os4 + oq * 64 + a;
      float* row = vchan + ((size_t)b * CINC + o) * PP;
      #pragma unroll
      for (int pq = 0; pq < 2; ++pq) {
        int p = p0 + ps4 + pq * 64;
        if (p < PP)
          *(float4*)&row[p] = make_float4(acc[oq][pq][a][0], acc[oq][pq][a][1],
                                          acc[oq][pq][a][2], acc[oq][pq][a][3]);
      }
    }
}

// ======================================================================
// K5: scores for bh = bh0 + blockIdx.z, writing into the local sim slab.
// 128i x 128j tile, 8x8 micro, + rel terms in epilogue.
// ======================================================================
__global__ __launch_bounds__(256) void k_sim(
    const float* __restrict__ qbuf, const float* __restrict__ kbuf,
    const float* __restrict__ qrh, const float* __restrict__ qrw,
    float* __restrict__ sim, int bh0)
{
  const int z = blockIdx.z;
  const int bh = bh0 + z;
  const size_t base = (size_t)bh * PP;          // q/k/rel indexing (global)
  const size_t sbase = (size_t)z * PP;          // sim slab indexing (local)
  const int i0 = blockIdx.y * 128, j0 = blockIdx.x * 128;
  __shared__ alignas(16) float als[8 * 132];
  __shared__ alignas(16) float bls[8 * 132];
  const int tid = threadIdx.x;
  const int is4 = (tid & 15) * 4, js4 = (tid >> 4) * 4;
  float acc[2][2][4][4];
  #pragma unroll
  for (int i = 0; i < 2; ++i)
    #pragma unroll
    for (int j = 0; j < 2; ++j)
      #pragma unroll
      for (int a = 0; a < 4; ++a)
        #pragma unroll
        for (int p = 0; p < 4; ++p) acc[i][j][a][p] = 0.f;

  const int ll = tid >> 1, ld4 = (tid & 1) * 4;
  const int ai = i0 + ll, bj = j0 + ll;

  for (int d0 = 0; d0 < DH; d0 += 8) {
    float4 av = (ai < PP) ? *(const float4*)&qbuf[(base + ai) * DH + d0 + ld4]
                          : make_float4(0.f, 0.f, 0.f, 0.f);
    float4 bv = (bj < PP) ? *(const float4*)&kbuf[(base + bj) * DH + d0 + ld4]
                          : make_float4(0.f, 0.f, 0.f, 0.f);
    __syncthreads();
    als[(ld4 + 0) * 132 + ll] = av.x;
    als[(ld4 + 1) * 132 + ll] = av.y;
    als[(ld4 + 2) * 132 + ll] = av.z;
    als[(ld4 + 3) * 132 + ll] = av.w;
    bls[(ld4 + 0) * 132 + ll] = bv.x;
    bls[(ld4 + 1) * 132 + ll] = bv.y;
    bls[(ld4 + 2) * 132 + ll] = bv.z;
    bls[(ld4 + 3) * 132 + ll] = bv.w;
    __syncthreads();
    #pragma unroll
    for (int kk = 0; kk < 8; ++kk) {
      const float4 a0 = *(const float4*)&als[kk * 132 + is4];
      const float4 a1 = *(const float4*)&als[kk * 132 + is4 + 64];
      const float4 b0 = *(const float4*)&bls[kk * 132 + js4];
      const float4 b1 = *(const float4*)&bls[kk * 132 + js4 + 64];
      FMAQ(acc[0][0], a0, b0) FMAQ(acc[0][1], a0, b1)
      FMAQ(acc[1][0], a1, b0) FMAQ(acc[1][1], a1, b1)
    }
  }
  #pragma unroll
  for (int iq = 0; iq < 2; ++iq)
    #pragma unroll
    for (int r = 0; r < 4; ++r) {
      const int i = i0 + is4 + iq * 64 + r;
      if (i >= PP) continue;
      const float* rh = &qrh[(base + i) * 44];
      const float* rw = &qrw[(base + i) * 44];
      float* dst = &sim[(sbase + i) * PP];
      #pragma unroll
      for (int jq = 0; jq < 2; ++jq) {
        const int jc = j0 + js4 + jq * 64;
        if (jc >= PP) continue;
        float4 o;
        o.x = acc[iq][jq][r][0] + rh[(jc + 0) / 44] + rw[(jc + 0) % 44];
        o.y = acc[iq][jq][r][1] + rh[(jc + 1) / 44] + rw[(jc + 1) % 44];
        o.z = acc[iq][jq][r][2] + rh[(jc + 2) / 44] + rw[(jc + 2) % 44];
        o.w = acc[iq][jq][r][3] + rh[(jc + 3) / 44] + rw[(jc + 3) % 44];
        *(float4*)&dst[jc] = o;
      }
    }
}

// ======================================================================
// K6: row softmax (unnormalized): sim = exp(sim - rowmax), rsum = rowsum.
// Operates on the local slab; rsum written at global row row0 + blockIdx.x.
// ======================================================================
__global__ __launch_bounds__(256) void k_softmax(
    float* __restrict__ sim, float* __restrict__ rsum, int row0)
{
  const size_t row = blockIdx.x;
  float4* p = (float4*)(sim + row * PP);      // 484 float4s
  const int tid = threadIdx.x;
  __shared__ float sred[4];

  float4 v0 = p[tid];
  float mx = fmaxf(fmaxf(v0.x, v0.y), fmaxf(v0.z, v0.w));
  const bool has2 = (tid + 256) < 484;
  float4 v1 = make_float4(0.f, 0.f, 0.f, 0.f);
  if (has2) {
    v1 = p[tid + 256];
    mx = fmaxf(mx, fmaxf(fmaxf(v1.x, v1.y), fmaxf(v1.z, v1.w)));
  }
  #pragma unroll
  for (int o = 32; o; o >>= 1) mx = fmaxf(mx, __shfl_xor(mx, o));
  if ((tid & 63) == 0) sred[tid >> 6] = mx;
  __syncthreads();
  mx = fmaxf(fmaxf(sred[0], sred[1]), fmaxf(sred[2], sred[3]));

  float sum;
  v0.x = __expf(v0.x - mx); v0.y = __expf(v0.y - mx);
  v0.z = __expf(v0.z - mx); v0.w = __expf(v0.w - mx);
  sum = v0.x + v0.y + v0.z + v0.w;
  p[tid] = v0;
  if (has2) {
    v1.x = __expf(v1.x - mx); v1.y = __expf(v1.y - mx);
    v1.z = __expf(v1.z - mx); v1.w = __expf(v1.w - mx);
    sum += v1.x + v1.y + v1.z + v1.w;
    p[tid + 256] = v1;
  }
  #pragma unroll
  for (int o = 32; o; o >>= 1) sum += __shfl_xor(sum, o);
  __syncthreads();
  if ((tid & 63) == 0) sred[tid >> 6] = sum;
  __syncthreads();
  if (tid == 0) rsum[row0 + row] = sred[0] + sred[1] + sred[2] + sred[3];
}

// ======================================================================
// K7: PV -> channel-major ochan[b][768][1936], normalization folded in.
// attn is the local slab; bh = bh0 + blockIdx.z. 128i x 64d, 8x4 micro.
// ======================================================================
__global__ __launch_bounds__(256) void k_pv(
    const float* __restrict__ attn, const float* __restrict__ vchan,
    const float* __restrict__ rsum, float* __restrict__ ochan, int bh0)
{
  const int z = blockIdx.z;
  const int bh = bh0 + z, b = bh >> 2, hd = bh & 3;
  const size_t abase = (size_t)z * PP;         // slab-local attn rows
  const size_t rbase = (size_t)bh * PP;        // global rsum rows
  const int d0 = blockIdx.x * 64, i0 = blockIdx.y * 128;
  __shared__ alignas(16) float als[16 * 132];
  __shared__ alignas(16) float bls[16 * 68];
  const int tid = threadIdx.x;
  const int is4 = (tid & 15) * 4, id4 = (tid >> 4) * 4;
  float acc[2][4][4];
  #pragma unroll
  for (int q = 0; q < 2; ++q)
    #pragma unroll
    for (int a = 0; a < 4; ++a)
      #pragma unroll
      for (int p = 0; p < 4; ++p) acc[q][a][p] = 0.f;

  const int lrow = tid >> 2, lk4 = (tid & 3) * 4;
  const int ai0 = i0 + lrow, ai1 = i0 + lrow + 64;
  const size_t vrow = ((size_t)b * CINC + hd * DH + d0 + lrow) * PP;

  for (int jc = 0; jc < PP; jc += 16) {
    float4 av0 = (ai0 < PP) ? *(const float4*)&attn[(abase + ai0) * PP + jc + lk4]
                            : make_float4(0.f, 0.f, 0.f, 0.f);
    float4 av1 = (ai1 < PP) ? *(const float4*)&attn[(abase + ai1) * PP + jc + lk4]
                            : make_float4(0.f, 0.f, 0.f, 0.f);
    float4 bv = *(const float4*)&vchan[vrow + jc + lk4];
    __syncthreads();
    als[(lk4 + 0) * 132 + lrow] = av0.x;
    als[(lk4 + 1) * 132 + lrow] = av0.y;
    als[(lk4 + 2) * 132 + lrow] = av0.z;
    als[(lk4 + 3) * 132 + lrow] = av0.w;
    als[(lk4 + 0) * 132 + lrow + 64] = av1.x;
    als[(lk4 + 1) * 132 + lrow + 64] = av1.y;
    als[(lk4 + 2) * 132 + lrow + 64] = av1.z;
    als[(lk4 + 3) * 132 + lrow + 64] = av1.w;
    bls[(lk4 + 0) * 68 + lrow] = bv.x;
    bls[(lk4 + 1) * 68 + lrow] = bv.y;
    bls[(lk4 + 2) * 68 + lrow] = bv.z;
    bls[(lk4 + 3) * 68 + lrow] = bv.w;
    __syncthreads();
    #pragma unroll
    for (int kk = 0; kk < 16; ++kk) {
      const float4 a0 = *(const float4*)&als[kk * 132 + is4];
      const float4 a1 = *(const float4*)&als[kk * 132 + is4 + 64];
      const float4 b0 = *(const float4*)&bls[kk * 68 + id4];
      FMAQ(acc[0], a0, b0) FMAQ(acc[1], a1, b0)
    }
  }
  float inv[2][4];
  #pragma unroll
  for (int q = 0; q < 2; ++q)
    #pragma unroll
    for (int r = 0; r < 4; ++r) {
      int i = i0 + is4 + q * 64 + r;
      inv[q][r] = (i < PP) ? 1.f / rsum[rbase + i] : 0.f;
    }
  #pragma unroll
  for (int q = 0; q < 2; ++q) {
    const int ib = i0 + is4 + q * 64;
    if (ib >= PP) continue;
    #pragma unroll
    for (int dp = 0; dp < 4; ++dp) {
      float4 o = make_float4(acc[q][0][dp] * inv[q][0], acc[q][1][dp] * inv[q][1],
                             acc[q][2][dp] * inv[q][2], acc[q][3][dp] * inv[q][3]);
      *(float4*)&ochan[((size_t)b * CINC + hd * DH + d0 + id4 + dp) * PP + ib] = o;
    }
  }
}

// ======================================================================
// K8: output projection + residual. B = ochan (contiguous float4 loads).
// ======================================================================
__global__ __launch_bounds__(256) void k_out(
    const float* __restrict__ x, const float* __restrict__ ochan,
    const float* __restrict__ wproj, const float* __restrict__ gamma,
    float* __restrict__ out)
{
  const int b = blockIdx.z;
  const int o0 = blockIdx.y * 128, p0 = blockIdx.x * 128;
  __shared__ alignas(16) float als[8 * 132];
  __shared__ alignas(16) float bls[8 * 132];
  const int tid = threadIdx.x;
  const int os4 = (tid & 15) * 4, ps4 = (tid >> 4) * 4;
  float acc[2][2][4][4];
  #pragma unroll
  for (int i = 0; i < 2; ++i)
    #pragma unroll
    for (int j = 0; j < 2; ++j)
      #pragma unroll
      for (int a = 0; a < 4; ++a)
        #pragma unroll
        for (int p = 0; p < 4; ++p) acc[i][j][a][p] = 0.f;

  const int aoo = tid >> 1, add = (tid & 1) * 4;
  const int bcc = tid >> 5;
  const int bp  = p0 + (tid & 31) * 4;
  const float* aptr = wproj + (size_t)(o0 + aoo) * CINC + add;

  for (int k0 = 0; k0 < CINC; k0 += 8) {
    float4 av = *(const float4*)(aptr + k0);
    float4 bv = (bp < PP)
        ? *(const float4*)&ochan[((size_t)b * CINC + k0 + bcc) * PP + bp]
        : make_float4(0.f, 0.f, 0.f, 0.f);
    __syncthreads();
    als[(add + 0) * 132 + aoo] = av.x;
    als[(add + 1) * 132 + aoo] = av.y;
    als[(add + 2) * 132 + aoo] = av.z;
    als[(add + 3) * 132 + aoo] = av.w;
    *(float4*)&bls[bcc * 132 + (tid & 31) * 4] = bv;
    __syncthreads();
    #pragma unroll
    for (int kk = 0; kk < 8; ++kk) {
      const float4 a0 = *(const float4*)&als[kk * 132 + os4];
      const float4 a1 = *(const float4*)&als[kk * 132 + os4 + 64];
      const float4 b0 = *(const float4*)&bls[kk * 132 + ps4];
      const float4 b1 = *(const float4*)&bls[kk * 132 + ps4 + 64];
      FMAQ(acc[0][0], a0, b0) FMAQ(acc[0][1], a0, b1)
      FMAQ(acc[1][0], a1, b0) FMAQ(acc[1][1], a1, b1)
    }
  }
  const float g = gamma[0];
  #pragma unroll
  for (int oq = 0; oq < 2; ++oq)
    #pragma unroll
    for (int a = 0; a < 4; ++a) {
      const int o = o0 + os4 + oq * 64 + a;
      const float* xr = &x[((size_t)b * CINC + o) * PP];
      float* dst = &out[((size_t)b * CINC + o) * PP];
      #pragma unroll
      for (int pq = 0; pq < 2; ++pq) {
        int p = p0 + ps4 + pq * 64;
        if (p < PP) {
          float4 xv = *(const float4*)&xr[p];
          *(float4*)&dst[p] = make_float4(xv.x + g * acc[oq][pq][a][0],
                                          xv.y + g * acc[oq][pq][a][1],
                                          xv.z + g * acc[oq][pq][a][2],
                                          xv.w + g * acc[oq][pq][a][3]);
        }
      }
    }
}

// ======================================================================
extern "C" void kernel_launch(void* const* d_in, const int* in_sizes, int n_in,
                              void* d_out, int out_size, void* d_ws, size_t ws_size,
                              hipStream_t stream)
{
  const float* x    = (const float*)d_in[0];
  const float* w3   = (const float*)d_in[1];
  const float* b3   = (const float*)d_in[2];
  const float* w5   = (const float*)d_in[3];
  const float* b5   = (const float*)d_in[4];
  const float* w7   = (const float*)d_in[5];
  const float* b7   = (const float*)d_in[6];
  const float* wqk  = (const float*)d_in[7];
  const float* relh = (const float*)d_in[8];
  const float* relw = (const float*)d_in[9];
  const float* wv   = (const float*)d_in[10];
  const float* wpr  = (const float*)d_in[11];
  const float* gam  = (const float*)d_in[12];
  float* out = (float*)d_out;
  float* ws  = (float*)d_ws;

  float* conv = ws + OFF_CONV;
  float* qb   = ws + OFF_Q;
  float* kb   = ws + OFF_K;
  float* vch  = ws + OFF_V;
  float* och  = ws + OFF_O;
  float* qrh  = ws + OFF_QRH;
  float* qrw  = ws + OFF_QRW;
  float* rs   = ws + OFF_RS;
  float* sim  = ws + OFF_SIM;

  // Pick the largest bh-group size whose sim slab fits the workspace.
  int g = 8;
  while (g > 1 && (OFF_SIM + (size_t)g * SIM_BH) * sizeof(float) > ws_size) g >>= 1;

  k_conv<<<dim3(36, 3, 6), 256, 0, stream>>>(x, w3, b3, w5, b5, w7, b7, conv);
  k_qk<<<dim3(16, 12, 2), 256, 0, stream>>>(x, conv, wqk, qb, kb);
  k_qrel<<<dim3(NB * NHD * PP), 128, 0, stream>>>(qb, relh, relw, qrh, qrw);
  k_v<<<dim3(16, 6, 2), 256, 0, stream>>>(x, wv, vch);

  for (int bh0 = 0; bh0 < NB * NHD; bh0 += g) {
    k_sim<<<dim3(16, 16, g), 256, 0, stream>>>(qb, kb, qrh, qrw, sim, bh0);
    k_softmax<<<dim3(g * PP), 256, 0, stream>>>(sim, rs, bh0 * PP);
    k_pv<<<dim3(3, 16, g), 256, 0, stream>>>(sim, vch, rs, och, bh0);
  }
  k_out<<<dim3(16, 6, 2), 256, 0, stream>>>(x, och, wpr, gam, out);
}

// Round 4
// 3051.429 us; speedup vs baseline: 1.6366x; 1.6366x over previous
//
#include <hip/hip_runtime.h>
#include <hip/hip_bf16.h>
#include <cstdint>
#include <cstddef>

// ---------------- problem constants ----------------
#define NB   2
#define CINC 768
#define PP   1936          // 44*44
#define CO   384
#define NHD  4
#define DH   192
#define FCH  1920          // 768 + 3*384
#define KCONV 6912         // 768*9

// ---------------- workspace layout (floats) ----------------
static const size_t OFF_CONV = 0;
static const size_t N_CONV   = (size_t)3 * NB * CO * PP;       // 4,460,544
static const size_t OFF_Q    = OFF_CONV + N_CONV;
static const size_t N_QKV    = (size_t)NB * NHD * PP * DH;     // 2,973,696
static const size_t OFF_K    = OFF_Q + N_QKV;
static const size_t OFF_V    = OFF_K + N_QKV;                  // channel-major [b][768][1936]
static const size_t OFF_O    = OFF_V + N_QKV;                  // channel-major [b][768][1936]
static const size_t OFF_QRH  = OFF_O + N_QKV;
static const size_t N_QR     = (size_t)NB * NHD * PP * 44;     // 681,472
static const size_t OFF_QRW  = OFF_QRH + N_QR;
static const size_t OFF_RS   = OFF_QRW + N_QR;                 // 15,488 rowsums
static const size_t OFF_WT   = OFF_RS + (size_t)NB * NHD * PP; // transposed conv weights
static const size_t N_WT     = (size_t)3 * KCONV * CO;         // 7,962,624
static const size_t OFF_SIM  = OFF_WT + N_WT;                  // slab: g*PP*PP
static const size_t SIM_BH   = (size_t)PP * PP;                // 3,748,096 per bh

// rank-1 outer-product accumulate: ACC[r][c] += A[r]*B[c]
#define FMAQ(ACC, A, B) { \
  ACC[0][0]+=A.x*B.x; ACC[0][1]+=A.x*B.y; ACC[0][2]+=A.x*B.z; ACC[0][3]+=A.x*B.w; \
  ACC[1][0]+=A.y*B.x; ACC[1][1]+=A.y*B.y; ACC[1][2]+=A.y*B.z; ACC[1][3]+=A.y*B.w; \
  ACC[2][0]+=A.z*B.x; ACC[2][1]+=A.z*B.y; ACC[2][2]+=A.z*B.z; ACC[2][3]+=A.z*B.w; \
  ACC[3][0]+=A.w*B.x; ACC[3][1]+=A.w*B.y; ACC[3][2]+=A.w*B.z; ACC[3][3]+=A.w*B.w; }

// ======================================================================
// K0: weight transpose  w[co][ci][3][3]  ->  wt[di][k=ci*9+tap][co]
// 64x64 LDS-tiled transpose; both global sides coalesced float4.
// grid (108, 6, 3), block 256.
// ======================================================================
__global__ __launch_bounds__(256) void k_wt(
    const float* __restrict__ w3, const float* __restrict__ w5,
    const float* __restrict__ w7, float* __restrict__ wt)
{
  const int di = blockIdx.z;
  const float* __restrict__ w = (di == 0) ? w3 : (di == 1 ? w5 : w7);
  float* __restrict__ dst = wt + (size_t)di * KCONV * CO;
  const int k0 = blockIdx.x * 64, co0 = blockIdx.y * 64;
  __shared__ alignas(16) float t[64 * 68];
  const int tid = threadIdx.x;
  #pragma unroll
  for (int r = 0; r < 4; ++r) {
    int co = (tid >> 4) + r * 16, k4 = (tid & 15) * 4;
    *(float4*)&t[co * 68 + k4] =
        *(const float4*)&w[(size_t)(co0 + co) * KCONV + k0 + k4];
  }
  __syncthreads();
  #pragma unroll
  for (int r = 0; r < 4; ++r) {
    int k = (tid >> 4) + r * 16, c4 = (tid & 15) * 4;
    float4 o = make_float4(t[(c4 + 0) * 68 + k], t[(c4 + 1) * 68 + k],
                           t[(c4 + 2) * 68 + k], t[(c4 + 3) * 68 + k]);
    *(float4*)&dst[(size_t)(k0 + k) * CO + co0 + c4] = o;
  }
}

// ======================================================================
// K1 v2: dilated 3x3 convs from transposed weights.
// Block: 128 co x 64 pos (8x8 spatial); thread = 8co (2 quadrants) x 4px.
// K-chunk = 4 ci (36 k-rows); register double-buffered staging.
// ======================================================================
template<int DIL>
__device__ __forceinline__ void conv_body(
    float* __restrict__ xs, float* __restrict__ wls,
    const float* __restrict__ xb, const float* __restrict__ wtd,
    const float* __restrict__ bia, float* __restrict__ outbase,
    int ty0, int tx0, int co0)
{
  constexpr int EXT = 8 + 2 * DIL;            // 14 / 18 / 22
  constexpr int EE  = EXT * EXT;              // 196 / 324 / 484
  constexpr int NXE = 4 * EE;                 // x floats per chunk
  constexpr int NX  = (NXE + 255) / 256;      // x slots per thread
  constexpr int NWF4 = 36 * 32;               // 1152 float4 per chunk (36k x 128co)
  constexpr int NW  = (NWF4 + 255) / 256;     // 5 w slots per thread

  const int tid = threadIdx.x;
  const int co_sub = (tid & 15) * 4;
  const int ps = (tid >> 4) * 4;
  const int py = ps >> 3, px0 = ps & 7;       // 8 rows x {0,4}

  float  xr[NX];
  float4 wr[NW];
  float acc[2][4][4];
  #pragma unroll
  for (int q = 0; q < 2; ++q)
    #pragma unroll
    for (int a = 0; a < 4; ++a)
      #pragma unroll
      for (int p = 0; p < 4; ++p) acc[q][a][p] = 0.f;

  // ---- stage-load chunk (global -> regs) ----
  auto stage_load = [&](int ci0) {
    #pragma unroll
    for (int s = 0; s < NX; ++s) {
      int e = tid + s * 256;
      xr[s] = 0.f;
      if (e < NXE) {
        int ci = e / EE, r = e - ci * EE;
        int row = r / EXT, col = r - row * EXT;
        int gy = ty0 - DIL + row, gx = tx0 - DIL + col;
        if ((unsigned)gy < 44u && (unsigned)gx < 44u)
          xr[s] = xb[(size_t)(ci0 + ci) * PP + gy * 44 + gx];
      }
    }
    #pragma unroll
    for (int s = 0; s < NW; ++s) {
      int e = tid + s * 256;
      if (e < NWF4) {
        int k = e >> 5, c4 = (e & 31) * 4;
        wr[s] = *(const float4*)&wtd[(size_t)(ci0 * 9 + k) * CO + co0 + c4];
      }
    }
  };
  // ---- stage-store chunk (regs -> LDS) ----
  auto stage_store = [&]() {
    #pragma unroll
    for (int s = 0; s < NX; ++s) {
      int e = tid + s * 256;
      if (e < NXE) xs[e] = xr[s];
    }
    #pragma unroll
    for (int s = 0; s < NW; ++s) {
      int e = tid + s * 256;
      if (e < NWF4) {
        int k = e >> 5, c4 = (e & 31) * 4;
        *(float4*)&wls[k * 132 + c4] = wr[s];
      }
    }
  };

  stage_load(0);
  for (int ci0 = 0; ci0 < CINC; ci0 += 4) {
    __syncthreads();                 // previous compute done; LDS reusable
    stage_store();
    __syncthreads();
    if (ci0 + 4 < CINC) stage_load(ci0 + 4);   // prefetch next while computing
    #pragma unroll
    for (int ci = 0; ci < 4; ++ci) {
      const float* xc = xs + ci * EE;
      #pragma unroll
      for (int kh = 0; kh < 3; ++kh) {
        const float* xrow = xc + (py + DIL * kh) * EXT + px0;
        #pragma unroll
        for (int kw = 0; kw < 3; ++kw) {
          const float* xq = xrow + DIL * kw;
          float4 xv = make_float4(xq[0], xq[1], xq[2], xq[3]);
          const int krow = ci * 9 + kh * 3 + kw;
          const float4 w0 = *(const float4*)&wls[krow * 132 + co_sub];
          const float4 w1 = *(const float4*)&wls[krow * 132 + co_sub + 64];
          FMAQ(acc[0], w0, xv)
          FMAQ(acc[1], w1, xv)
        }
      }
    }
  }

  const int gy = ty0 + py;
  const int gx0 = tx0 + px0;
  if (gy < 44 && gx0 < 44) {
    #pragma unroll
    for (int q = 0; q < 2; ++q)
      #pragma unroll
      for (int a = 0; a < 4; ++a) {
        const int co = co0 + co_sub + q * 64 + a;
        const float bv = bia[co];
        *(float4*)&outbase[(size_t)co * PP + gy * 44 + gx0] =
            make_float4(acc[q][a][0] + bv, acc[q][a][1] + bv,
                        acc[q][a][2] + bv, acc[q][a][3] + bv);
      }
  }
}

__global__ __launch_bounds__(256) void k_conv(
    const float* __restrict__ x, const float* __restrict__ wt,
    const float* __restrict__ b3, const float* __restrict__ b5,
    const float* __restrict__ b7, float* __restrict__ conv_out)
{
  __shared__ alignas(16) float xs[4 * 484];        // max EE (dil=7)
  __shared__ alignas(16) float wls[36 * 132];
  const int zt = blockIdx.z, di = zt >> 1, b = zt & 1;
  const int pt = blockIdx.x;
  const int ty0 = (pt / 6) * 8, tx0 = (pt % 6) * 8;
  const int co0 = blockIdx.y * 128;
  const float* xb  = x + (size_t)b * CINC * PP;
  const float* wtd = wt + (size_t)di * KCONV * CO;
  const float* bia = (di == 0) ? b3 : (di == 1 ? b5 : b7);
  float* outbase = conv_out + (size_t)(di * NB + b) * CO * PP;
  if (di == 0)      conv_body<3>(xs, wls, xb, wtd, bia, outbase, ty0, tx0, co0);
  else if (di == 1) conv_body<5>(xs, wls, xb, wtd, bia, outbase, ty0, tx0, co0);
  else              conv_body<7>(xs, wls, xb, wtd, bia, outbase, ty0, tx0, co0);
}

// ======================================================================
// K2: qk projection, 128o x 128p tile, 8x8 micro (2x2 quadrants).
// Writes q (scaled 0.5) and k in head layout [bh][pos][192].
// ======================================================================
__global__ __launch_bounds__(256) void k_qk(
    const float* __restrict__ x, const float* __restrict__ conv,
    const float* __restrict__ wqk,
    float* __restrict__ qbuf, float* __restrict__ kbuf)
{
  const int b = blockIdx.z;
  const int o0 = blockIdx.y * 128, p0 = blockIdx.x * 128;
  __shared__ alignas(16) float als[8 * 132];
  __shared__ alignas(16) float bls[8 * 132];
  const int tid = threadIdx.x;
  const int os4 = (tid & 15) * 4, ps4 = (tid >> 4) * 4;
  float acc[2][2][4][4];
  #pragma unroll
  for (int i = 0; i < 2; ++i)
    #pragma unroll
    for (int j = 0; j < 2; ++j)
      #pragma unroll
      for (int a = 0; a < 4; ++a)
        #pragma unroll
        for (int p = 0; p < 4; ++p) acc[i][j][a][p] = 0.f;

  const int aoo = tid >> 1, add = (tid & 1) * 4;
  const int bcc = tid >> 5;
  const int bp  = p0 + (tid & 31) * 4;
  const float* aptr = wqk + (size_t)(o0 + aoo) * FCH + add;

  for (int k0 = 0; k0 < FCH; k0 += 8) {
    float4 av = *(const float4*)(aptr + k0);
    float4 bv = make_float4(0.f, 0.f, 0.f, 0.f);
    {
      int c = k0 + bcc;
      if (bp < PP) {
        const float* src;
        if (c < CINC) src = x + ((size_t)b * CINC + c) * PP;
        else {
          int c2 = c - CINC; int dd2 = c2 / CO, cc2 = c2 - dd2 * CO;
          src = conv + ((size_t)(dd2 * NB + b) * CO + cc2) * PP;
        }
        bv = *(const float4*)(src + bp);
      }
    }
    __syncthreads();
    als[(add + 0) * 132 + aoo] = av.x;
    als[(add + 1) * 132 + aoo] = av.y;
    als[(add + 2) * 132 + aoo] = av.z;
    als[(add + 3) * 132 + aoo] = av.w;
    *(float4*)&bls[bcc * 132 + (tid & 31) * 4] = bv;
    __syncthreads();
    #pragma unroll
    for (int kk = 0; kk < 8; ++kk) {
      const float4 a0 = *(const float4*)&als[kk * 132 + os4];
      const float4 a1 = *(const float4*)&als[kk * 132 + os4 + 64];
      const float4 b0 = *(const float4*)&bls[kk * 132 + ps4];
      const float4 b1 = *(const float4*)&bls[kk * 132 + ps4 + 64];
      FMAQ(acc[0][0], a0, b0) FMAQ(acc[0][1], a0, b1)
      FMAQ(acc[1][0], a1, b0) FMAQ(acc[1][1], a1, b1)
    }
  }
  #pragma unroll
  for (int oq = 0; oq < 2; ++oq)
    #pragma unroll
    for (int a = 0; a < 4; ++a) {
      const int o = o0 + os4 + oq * 64 + a;
      const bool isq = (o < CINC);
      const int oo = isq ? o : o - CINC;
      const int hd = oo / DH, dd = oo - hd * DH;
      float* dst = (isq ? qbuf : kbuf) + ((size_t)(b * NHD + hd) * PP) * DH + dd;
      const float s = isq ? 0.5f : 1.0f;      // HEAD^-0.5 = 0.5
      #pragma unroll
      for (int pq = 0; pq < 2; ++pq)
        #pragma unroll
        for (int pi = 0; pi < 4; ++pi) {
          int pp = p0 + ps4 + pq * 64 + pi;
          if (pp < PP) dst[(size_t)pp * DH] = acc[oq][pq][a][pi] * s;
        }
    }
}

// ======================================================================
// K3: rel-pos dot products (uses scaled q, matching reference).
// ======================================================================
__global__ __launch_bounds__(128) void k_qrel(
    const float* __restrict__ qbuf, const float* __restrict__ relh,
    const float* __restrict__ relw,
    float* __restrict__ qrh, float* __restrict__ qrw)
{
  const int bh = blockIdx.x / PP, pos = blockIdx.x % PP;
  const int xr = pos / 44, yc = pos - 44 * xr;
  __shared__ alignas(16) float qs[192];
  const int tid = threadIdx.x;
  for (int e = tid; e < 192; e += 128)
    qs[e] = qbuf[((size_t)bh * PP + pos) * DH + e];
  __syncthreads();
  const float4* q4 = (const float4*)qs;
  if (tid < 44) {
    const float4* r4 = (const float4*)&relh[(size_t)(tid - xr + 99) * DH];
    float s = 0.f;
    #pragma unroll
    for (int d = 0; d < 48; ++d) {
      float4 a = q4[d], bb = r4[d];
      s += a.x * bb.x + a.y * bb.y + a.z * bb.z + a.w * bb.w;
    }
    qrh[((size_t)bh * PP + pos) * 44 + tid] = s;
  } else if (tid >= 64 && tid < 108) {
    const int v = tid - 64;
    const float4* r4 = (const float4*)&relw[(size_t)(v - yc + 99) * DH];
    float s = 0.f;
    #pragma unroll
    for (int d = 0; d < 48; ++d) {
      float4 a = q4[d], bb = r4[d];
      s += a.x * bb.x + a.y * bb.y + a.z * bb.z + a.w * bb.w;
    }
    qrw[((size_t)bh * PP + pos) * 44 + v] = s;
  }
}

// ======================================================================
// K4: v projection -> channel-major vchan[b][768][1936].
// ======================================================================
__global__ __launch_bounds__(256) void k_v(
    const float* __restrict__ x, const float* __restrict__ wv,
    float* __restrict__ vchan)
{
  const int b = blockIdx.z;
  const int o0 = blockIdx.y * 128, p0 = blockIdx.x * 128;
  __shared__ alignas(16) float als[8 * 132];
  __shared__ alignas(16) float bls[8 * 132];
  const int tid = threadIdx.x;
  const int os4 = (tid & 15) * 4, ps4 = (tid >> 4) * 4;
  float acc[2][2][4][4];
  #pragma unroll
  for (int i = 0; i < 2; ++i)
    #pragma unroll
    for (int j = 0; j < 2; ++j)
      #pragma unroll
      for (int a = 0; a < 4; ++a)
        #pragma unroll
        for (int p = 0; p < 4; ++p) acc[i][j][a][p] = 0.f;

  const int aoo = tid >> 1, add = (tid & 1) * 4;
  const int bcc = tid >> 5;
  const int bp  = p0 + (tid & 31) * 4;
  const float* aptr = wv + (size_t)(o0 + aoo) * CINC + add;

  for (int k0 = 0; k0 < CINC; k0 += 8) {
    float4 av = *(const float4*)(aptr + k0);
    float4 bv = (bp < PP)
        ? *(const float4*)&x[((size_t)b * CINC + k0 + bcc) * PP + bp]
        : make_float4(0.f, 0.f, 0.f, 0.f);
    __syncthreads();
    als[(add + 0) * 132 + aoo] = av.x;
    als[(add + 1) * 132 + aoo] = av.y;
    als[(add + 2) * 132 + aoo] = av.z;
    als[(add + 3) * 132 + aoo] = av.w;
    *(float4*)&bls[bcc * 132 + (tid & 31) * 4] = bv;
    __syncthreads();
    #pragma unroll
    for (int kk = 0; kk < 8; ++kk) {
      const float4 a0 = *(const float4*)&als[kk * 132 + os4];
      const float4 a1 = *(const float4*)&als[kk * 132 + os4 + 64];
      const float4 b0 = *(const float4*)&bls[kk * 132 + ps4];
      const float4 b1 = *(const float4*)&bls[kk * 132 + ps4 + 64];
      FMAQ(acc[0][0], a0, b0) FMAQ(acc[0][1], a0, b1)
      FMAQ(acc[1][0], a1, b0) FMAQ(acc[1][1], a1, b1)
    }
  }
  #pragma unroll
  for (int oq = 0; oq < 2; ++oq)
    #pragma unroll
    for (int a = 0; a < 4; ++a) {
      const int o = o0 + os4 + oq * 64 + a;
      float* row = vchan + ((size_t)b * CINC + o) * PP;
      #pragma unroll
      for (int pq = 0; pq < 2; ++pq) {
        int p = p0 + ps4 + pq * 64;
        if (p < PP)
          *(float4*)&row[p] = make_float4(acc[oq][pq][a][0], acc[oq][pq][a][1],
                                          acc[oq][pq][a][2], acc[oq][pq][a][3]);
      }
    }
}

// ======================================================================
// K5: scores for bh = bh0 + blockIdx.z, writing into the local sim slab.
// ======================================================================
__global__ __launch_bounds__(256) void k_sim(
    const float* __restrict__ qbuf, const float* __restrict__ kbuf,
    const float* __restrict__ qrh, const float* __restrict__ qrw,
    float* __restrict__ sim, int bh0)
{
  const int z = blockIdx.z;
  const int bh = bh0 + z;
  const size_t base = (size_t)bh * PP;          // q/k/rel indexing (global)
  const size_t sbase = (size_t)z * PP;          // sim slab indexing (local)
  const int i0 = blockIdx.y * 128, j0 = blockIdx.x * 128;
  __shared__ alignas(16) float als[8 * 132];
  __shared__ alignas(16) float bls[8 * 132];
  const int tid = threadIdx.x;
  const int is4 = (tid & 15) * 4, js4 = (tid >> 4) * 4;
  float acc[2][2][4][4];
  #pragma unroll
  for (int i = 0; i < 2; ++i)
    #pragma unroll
    for (int j = 0; j < 2; ++j)
      #pragma unroll
      for (int a = 0; a < 4; ++a)
        #pragma unroll
        for (int p = 0; p < 4; ++p) acc[i][j][a][p] = 0.f;

  const int ll = tid >> 1, ld4 = (tid & 1) * 4;
  const int ai = i0 + ll, bj = j0 + ll;

  for (int d0 = 0; d0 < DH; d0 += 8) {
    float4 av = (ai < PP) ? *(const float4*)&qbuf[(base + ai) * DH + d0 + ld4]
                          : make_float4(0.f, 0.f, 0.f, 0.f);
    float4 bv = (bj < PP) ? *(const float4*)&kbuf[(base + bj) * DH + d0 + ld4]
                          : make_float4(0.f, 0.f, 0.f, 0.f);
    __syncthreads();
    als[(ld4 + 0) * 132 + ll] = av.x;
    als[(ld4 + 1) * 132 + ll] = av.y;
    als[(ld4 + 2) * 132 + ll] = av.z;
    als[(ld4 + 3) * 132 + ll] = av.w;
    bls[(ld4 + 0) * 132 + ll] = bv.x;
    bls[(ld4 + 1) * 132 + ll] = bv.y;
    bls[(ld4 + 2) * 132 + ll] = bv.z;
    bls[(ld4 + 3) * 132 + ll] = bv.w;
    __syncthreads();
    #pragma unroll
    for (int kk = 0; kk < 8; ++kk) {
      const float4 a0 = *(const float4*)&als[kk * 132 + is4];
      const float4 a1 = *(const float4*)&als[kk * 132 + is4 + 64];
      const float4 b0 = *(const float4*)&bls[kk * 132 + js4];
      const float4 b1 = *(const float4*)&bls[kk * 132 + js4 + 64];
      FMAQ(acc[0][0], a0, b0) FMAQ(acc[0][1], a0, b1)
      FMAQ(acc[1][0], a1, b0) FMAQ(acc[1][1], a1, b1)
    }
  }
  #pragma unroll
  for (int iq = 0; iq < 2; ++iq)
    #pragma unroll
    for (int r = 0; r < 4; ++r) {
      const int i = i0 + is4 + iq * 64 + r;
      if (i >= PP) continue;
      const float* rh = &qrh[(base + i) * 44];
      const float* rw = &qrw[(base + i) * 44];
      float* dst = &sim[(sbase + i) * PP];
      #pragma unroll
      for (int jq = 0; jq < 2; ++jq) {
        const int jc = j0 + js4 + jq * 64;
        if (jc >= PP) continue;
        float4 o;
        o.x = acc[iq][jq][r][0] + rh[(jc + 0) / 44] + rw[(jc + 0) % 44];
        o.y = acc[iq][jq][r][1] + rh[(jc + 1) / 44] + rw[(jc + 1) % 44];
        o.z = acc[iq][jq][r][2] + rh[(jc + 2) / 44] + rw[(jc + 2) % 44];
        o.w = acc[iq][jq][r][3] + rh[(jc + 3) / 44] + rw[(jc + 3) % 44];
        *(float4*)&dst[jc] = o;
      }
    }
}

// ======================================================================
// K6: row softmax (unnormalized): sim = exp(sim - rowmax), rsum = rowsum.
// ======================================================================
__global__ __launch_bounds__(256) void k_softmax(
    float* __restrict__ sim, float* __restrict__ rsum, int row0)
{
  const size_t row = blockIdx.x;
  float4* p = (float4*)(sim + row * PP);      // 484 float4s
  const int tid = threadIdx.x;
  __shared__ float sred[4];

  float4 v0 = p[tid];
  float mx = fmaxf(fmaxf(v0.x, v0.y), fmaxf(v0.z, v0.w));
  const bool has2 = (tid + 256) < 484;
  float4 v1 = make_float4(0.f, 0.f, 0.f, 0.f);
  if (has2) {
    v1 = p[tid + 256];
    mx = fmaxf(mx, fmaxf(fmaxf(v1.x, v1.y), fmaxf(v1.z, v1.w)));
  }
  #pragma unroll
  for (int o = 32; o; o >>= 1) mx = fmaxf(mx, __shfl_xor(mx, o));
  if ((tid & 63) == 0) sred[tid >> 6] = mx;
  __syncthreads();
  mx = fmaxf(fmaxf(sred[0], sred[1]), fmaxf(sred[2], sred[3]));

  float sum;
  v0.x = __expf(v0.x - mx); v0.y = __expf(v0.y - mx);
  v0.z = __expf(v0.z - mx); v0.w = __expf(v0.w - mx);
  sum = v0.x + v0.y + v0.z + v0.w;
  p[tid] = v0;
  if (has2) {
    v1.x = __expf(v1.x - mx); v1.y = __expf(v1.y - mx);
    v1.z = __expf(v1.z - mx); v1.w = __expf(v1.w - mx);
    sum += v1.x + v1.y + v1.z + v1.w;
    p[tid + 256] = v1;
  }
  #pragma unroll
  for (int o = 32; o; o >>= 1) sum += __shfl_xor(sum, o);
  __syncthreads();
  if ((tid & 63) == 0) sred[tid >> 6] = sum;
  __syncthreads();
  if (tid == 0) rsum[row0 + row] = sred[0] + sred[1] + sred[2] + sred[3];
}

// ======================================================================
// K7: PV -> channel-major ochan[b][768][1936], normalization folded in.
// ======================================================================
__global__ __launch_bounds__(256) void k_pv(
    const float* __restrict__ attn, const float* __restrict__ vchan,
    const float* __restrict__ rsum, float* __restrict__ ochan, int bh0)
{
  const int z = blockIdx.z;
  const int bh = bh0 + z, b = bh >> 2, hd = bh & 3;
  const size_t abase = (size_t)z * PP;         // slab-local attn rows
  const size_t rbase = (size_t)bh * PP;        // global rsum rows
  const int d0 = blockIdx.x * 64, i0 = blockIdx.y * 128;
  __shared__ alignas(16) float als[16 * 132];
  __shared__ alignas(16) float bls[16 * 68];
  const int tid = threadIdx.x;
  const int is4 = (tid & 15) * 4, id4 = (tid >> 4) * 4;
  float acc[2][4][4];
  #pragma unroll
  for (int q = 0; q < 2; ++q)
    #pragma unroll
    for (int a = 0; a < 4; ++a)
      #pragma unroll
      for (int p = 0; p < 4; ++p) acc[q][a][p] = 0.f;

  const int lrow = tid >> 2, lk4 = (tid & 3) * 4;
  const int ai0 = i0 + lrow, ai1 = i0 + lrow + 64;
  const size_t vrow = ((size_t)b * CINC + hd * DH + d0 + lrow) * PP;

  for (int jc = 0; jc < PP; jc += 16) {
    float4 av0 = (ai0 < PP) ? *(const float4*)&attn[(abase + ai0) * PP + jc + lk4]
                            : make_float4(0.f, 0.f, 0.f, 0.f);
    float4 av1 = (ai1 < PP) ? *(const float4*)&attn[(abase + ai1) * PP + jc + lk4]
                            : make_float4(0.f, 0.f, 0.f, 0.f);
    float4 bv = *(const float4*)&vchan[vrow + jc + lk4];
    __syncthreads();
    als[(lk4 + 0) * 132 + lrow] = av0.x;
    als[(lk4 + 1) * 132 + lrow] = av0.y;
    als[(lk4 + 2) * 132 + lrow] = av0.z;
    als[(lk4 + 3) * 132 + lrow] = av0.w;
    als[(lk4 + 0) * 132 + lrow + 64] = av1.x;
    als[(lk4 + 1) * 132 + lrow + 64] = av1.y;
    als[(lk4 + 2) * 132 + lrow + 64] = av1.z;
    als[(lk4 + 3) * 132 + lrow + 64] = av1.w;
    bls[(lk4 + 0) * 68 + lrow] = bv.x;
    bls[(lk4 + 1) * 68 + lrow] = bv.y;
    bls[(lk4 + 2) * 68 + lrow] = bv.z;
    bls[(lk4 + 3) * 68 + lrow] = bv.w;
    __syncthreads();
    #pragma unroll
    for (int kk = 0; kk < 16; ++kk) {
      const float4 a0 = *(const float4*)&als[kk * 132 + is4];
      const float4 a1 = *(const float4*)&als[kk * 132 + is4 + 64];
      const float4 b0 = *(const float4*)&bls[kk * 68 + id4];
      FMAQ(acc[0], a0, b0) FMAQ(acc[1], a1, b0)
    }
  }
  float inv[2][4];
  #pragma unroll
  for (int q = 0; q < 2; ++q)
    #pragma unroll
    for (int r = 0; r < 4; ++r) {
      int i = i0 + is4 + q * 64 + r;
      inv[q][r] = (i < PP) ? 1.f / rsum[rbase + i] : 0.f;
    }
  #pragma unroll
  for (int q = 0; q < 2; ++q) {
    const int ib = i0 + is4 + q * 64;
    if (ib >= PP) continue;
    #pragma unroll
    for (int dp = 0; dp < 4; ++dp) {
      float4 o = make_float4(acc[q][0][dp] * inv[q][0], acc[q][1][dp] * inv[q][1],
                             acc[q][2][dp] * inv[q][2], acc[q][3][dp] * inv[q][3]);
      *(float4*)&ochan[((size_t)b * CINC + hd * DH + d0 + id4 + dp) * PP + ib] = o;
    }
  }
}

// ======================================================================
// K8: output projection + residual. B = ochan (contiguous float4 loads).
// ======================================================================
__global__ __launch_bounds__(256) void k_out(
    const float* __restrict__ x, const float* __restrict__ ochan,
    const float* __restrict__ wproj, const float* __restrict__ gamma,
    float* __restrict__ out)
{
  const int b = blockIdx.z;
  const int o0 = blockIdx.y * 128, p0 = blockIdx.x * 128;
  __shared__ alignas(16) float als[8 * 132];
  __shared__ alignas(16) float bls[8 * 132];
  const int tid = threadIdx.x;
  const int os4 = (tid & 15) * 4, ps4 = (tid >> 4) * 4;
  float acc[2][2][4][4];
  #pragma unroll
  for (int i = 0; i < 2; ++i)
    #pragma unroll
    for (int j = 0; j < 2; ++j)
      #pragma unroll
      for (int a = 0; a < 4; ++a)
        #pragma unroll
        for (int p = 0; p < 4; ++p) acc[i][j][a][p] = 0.f;

  const int aoo = tid >> 1, add = (tid & 1) * 4;
  const int bcc = tid >> 5;
  const int bp  = p0 + (tid & 31) * 4;
  const float* aptr = wproj + (size_t)(o0 + aoo) * CINC + add;

  for (int k0 = 0; k0 < CINC; k0 += 8) {
    float4 av = *(const float4*)(aptr + k0);
    float4 bv = (bp < PP)
        ? *(const float4*)&ochan[((size_t)b * CINC + k0 + bcc) * PP + bp]
        : make_float4(0.f, 0.f, 0.f, 0.f);
    __syncthreads();
    als[(add + 0) * 132 + aoo] = av.x;
    als[(add + 1) * 132 + aoo] = av.y;
    als[(add + 2) * 132 + aoo] = av.z;
    als[(add + 3) * 132 + aoo] = av.w;
    *(float4*)&bls[bcc * 132 + (tid & 31) * 4] = bv;
    __syncthreads();
    #pragma unroll
    for (int kk = 0; kk < 8; ++kk) {
      const float4 a0 = *(const float4*)&als[kk * 132 + os4];
      const float4 a1 = *(const float4*)&als[kk * 132 + os4 + 64];
      const float4 b0 = *(const float4*)&bls[kk * 132 + ps4];
      const float4 b1 = *(const float4*)&bls[kk * 132 + ps4 + 64];
      FMAQ(acc[0][0], a0, b0) FMAQ(acc[0][1], a0, b1)
      FMAQ(acc[1][0], a1, b0) FMAQ(acc[1][1], a1, b1)
    }
  }
  const float g = gamma[0];
  #pragma unroll
  for (int oq = 0; oq < 2; ++oq)
    #pragma unroll
    for (int a = 0; a < 4; ++a) {
      const int o = o0 + os4 + oq * 64 + a;
      const float* xr = &x[((size_t)b * CINC + o) * PP];
      float* dst = &out[((size_t)b * CINC + o) * PP];
      #pragma unroll
      for (int pq = 0; pq < 2; ++pq) {
        int p = p0 + ps4 + pq * 64;
        if (p < PP) {
          float4 xv = *(const float4*)&xr[p];
          *(float4*)&dst[p] = make_float4(xv.x + g * acc[oq][pq][a][0],
                                          xv.y + g * acc[oq][pq][a][1],
                                          xv.z + g * acc[oq][pq][a][2],
                                          xv.w + g * acc[oq][pq][a][3]);
        }
      }
    }
}

// ======================================================================
extern "C" void kernel_launch(void* const* d_in, const int* in_sizes, int n_in,
                              void* d_out, int out_size, void* d_ws, size_t ws_size,
                              hipStream_t stream)
{
  const float* x    = (const float*)d_in[0];
  const float* w3   = (const float*)d_in[1];
  const float* b3   = (const float*)d_in[2];
  const float* w5   = (const float*)d_in[3];
  const float* b5   = (const float*)d_in[4];
  const float* w7   = (const float*)d_in[5];
  const float* b7   = (const float*)d_in[6];
  const float* wqk  = (const float*)d_in[7];
  const float* relh = (const float*)d_in[8];
  const float* relw = (const float*)d_in[9];
  const float* wv   = (const float*)d_in[10];
  const float* wpr  = (const float*)d_in[11];
  const float* gam  = (const float*)d_in[12];
  float* out = (float*)d_out;
  float* ws  = (float*)d_ws;

  float* conv = ws + OFF_CONV;
  float* qb   = ws + OFF_Q;
  float* kb   = ws + OFF_K;
  float* vch  = ws + OFF_V;
  float* och  = ws + OFF_O;
  float* qrh  = ws + OFF_QRH;
  float* qrw  = ws + OFF_QRW;
  float* rs   = ws + OFF_RS;
  float* wt   = ws + OFF_WT;
  float* sim  = ws + OFF_SIM;

  // Pick the largest bh-group size whose sim slab fits the workspace.
  int g = 8;
  while (g > 1 && (OFF_SIM + (size_t)g * SIM_BH) * sizeof(float) > ws_size) g >>= 1;

  k_wt<<<dim3(108, 6, 3), 256, 0, stream>>>(w3, w5, w7, wt);
  k_conv<<<dim3(36, 3, 6), 256, 0, stream>>>(x, wt, b3, b5, b7, conv);
  k_qk<<<dim3(16, 12, 2), 256, 0, stream>>>(x, conv, wqk, qb, kb);
  k_qrel<<<dim3(NB * NHD * PP), 128, 0, stream>>>(qb, relh, relw, qrh, qrw);
  k_v<<<dim3(16, 6, 2), 256, 0, stream>>>(x, wv, vch);

  for (int bh0 = 0; bh0 < NB * NHD; bh0 += g) {
    k_sim<<<dim3(16, 16, g), 256, 0, stream>>>(qb, kb, qrh, qrw, sim, bh0);
    k_softmax<<<dim3(g * PP), 256, 0, stream>>>(sim, rs, bh0 * PP);
    k_pv<<<dim3(3, 16, g), 256, 0, stream>>>(sim, vch, rs, och, bh0);
  }
  k_out<<<dim3(16, 6, 2), 256, 0, stream>>>(x, och, wpr, gam, out);
}

// Round 8
// 2519.246 us; speedup vs baseline: 1.9823x; 1.2112x over previous
//
#include <hip/hip_runtime.h>
#include <hip/hip_bf16.h>
#include <cstdint>
#include <cstddef>

// ---------------- problem constants ----------------
#define NB   2
#define CINC 768
#define PP   1936          // 44*44
#define CO   384
#define NHD  4
#define DH   192
#define FCH  1920          // 768 + 3*384
#define KCONV 6912         // 768*9
#define PPAD 1952          // PP padded to 61*32 (bf16 P row stride)

typedef __attribute__((ext_vector_type(8))) short short8v;   // 8 bf16
typedef __attribute__((ext_vector_type(4))) float f32x4;     // MFMA acc

__device__ __forceinline__ ushort f2bf(float f) {
  union { float f; unsigned u; } c; c.f = f;
  unsigned b = c.u;
  return (ushort)((b + 0x7FFFu + ((b >> 16) & 1u)) >> 16);   // RNE
}

// ---------------- workspace layout (floats) ----------------
static const size_t OFF_CONV = 0;
static const size_t N_CONV   = (size_t)3 * NB * CO * PP;       // 4,460,544
static const size_t OFF_Q    = OFF_CONV + N_CONV;
static const size_t N_QKV    = (size_t)NB * NHD * PP * DH;     // 2,973,696
static const size_t OFF_K    = OFF_Q + N_QKV;                  // region reused: qbf+kbf (bf16)
static const size_t OFF_V    = OFF_K + N_QKV;                  // vchan fp32 channel-major
static const size_t OFF_O    = OFF_V + N_QKV;                  // obuf fp32 [bh][pos][192]
static const size_t OFF_QRH  = OFF_O + N_QKV;
static const size_t N_QR     = (size_t)NB * NHD * PP * 44;     // 681,472
static const size_t OFF_QRW  = OFF_QRH + N_QR;
static const size_t OFF_RS   = OFF_QRW + N_QR;                 // 15,488 rowsums
static const size_t OFF_WT   = OFF_RS + (size_t)NB * NHD * PP; // transposed conv weights
static const size_t N_WT     = (size_t)3 * KCONV * CO;         // 7,962,624
static const size_t OFF_SIM  = OFF_WT + N_WT;                  // slab: g*PP*PP fp32, then pbf bf16
static const size_t SIM_BH   = (size_t)PP * PP;                // 3,748,096 per bh

// rank-1 outer-product accumulate: ACC[r][c] += A[r]*B[c]
#define FMAQ(ACC, A, B) { \
  ACC[0][0]+=A.x*B.x; ACC[0][1]+=A.x*B.y; ACC[0][2]+=A.x*B.z; ACC[0][3]+=A.x*B.w; \
  ACC[1][0]+=A.y*B.x; ACC[1][1]+=A.y*B.y; ACC[1][2]+=A.y*B.z; ACC[1][3]+=A.y*B.w; \
  ACC[2][0]+=A.z*B.x; ACC[2][1]+=A.z*B.y; ACC[2][2]+=A.z*B.z; ACC[2][3]+=A.z*B.w; \
  ACC[3][0]+=A.w*B.x; ACC[3][1]+=A.w*B.y; ACC[3][2]+=A.w*B.z; ACC[3][3]+=A.w*B.w; }

// ======================================================================
// K0: weight transpose  w[co][ci][3][3] -> wt[di][k=ci*9+tap][co]
// ======================================================================
__global__ __launch_bounds__(256) void k_wt(
    const float* __restrict__ w3, const float* __restrict__ w5,
    const float* __restrict__ w7, float* __restrict__ wt)
{
  const int di = blockIdx.z;
  const float* __restrict__ w = (di == 0) ? w3 : (di == 1 ? w5 : w7);
  float* __restrict__ dst = wt + (size_t)di * KCONV * CO;
  const int k0 = blockIdx.x * 64, co0 = blockIdx.y * 64;
  __shared__ alignas(16) float t[64 * 68];
  const int tid = threadIdx.x;
  #pragma unroll
  for (int r = 0; r < 4; ++r) {
    int co = (tid >> 4) + r * 16, k4 = (tid & 15) * 4;
    *(float4*)&t[co * 68 + k4] =
        *(const float4*)&w[(size_t)(co0 + co) * KCONV + k0 + k4];
  }
  __syncthreads();
  #pragma unroll
  for (int r = 0; r < 4; ++r) {
    int k = (tid >> 4) + r * 16, c4 = (tid & 15) * 4;
    float4 o = make_float4(t[(c4 + 0) * 68 + k], t[(c4 + 1) * 68 + k],
                           t[(c4 + 2) * 68 + k], t[(c4 + 3) * 68 + k]);
    *(float4*)&dst[(size_t)(k0 + k) * CO + co0 + c4] = o;
  }
}

// ======================================================================
// K1 v3: dilated convs, 64co x 64pos tiles for occupancy (grid 1296).
// ======================================================================
template<int DIL>
__device__ __forceinline__ void conv_body(
    float* __restrict__ xs, float* __restrict__ wls,
    const float* __restrict__ xb, const float* __restrict__ wtd,
    const float* __restrict__ bia, float* __restrict__ outbase,
    int ty0, int tx0, int co0)
{
  constexpr int EXT = 8 + 2 * DIL;
  constexpr int EE  = EXT * EXT;
  constexpr int NXE = 4 * EE;
  constexpr int NX  = (NXE + 255) / 256;
  constexpr int NWF4 = 36 * 16;               // 576 float4 (36 k x 64 co)
  constexpr int NW  = 3;

  const int tid = threadIdx.x;
  const int co_sub = (tid & 15) * 4;
  const int ps = (tid >> 4) * 4;
  const int py = ps >> 3, px0 = ps & 7;

  float  xr[NX];
  float4 wr[NW];
  float acc[4][4];
  #pragma unroll
  for (int a = 0; a < 4; ++a)
    #pragma unroll
    for (int p = 0; p < 4; ++p) acc[a][p] = 0.f;

  auto stage_load = [&](int ci0) {
    #pragma unroll
    for (int s = 0; s < NX; ++s) {
      int e = tid + s * 256;
      xr[s] = 0.f;
      if (e < NXE) {
        int ci = e / EE, r = e - ci * EE;
        int row = r / EXT, col = r - row * EXT;
        int gy = ty0 - DIL + row, gx = tx0 - DIL + col;
        if ((unsigned)gy < 44u && (unsigned)gx < 44u)
          xr[s] = xb[(size_t)(ci0 + ci) * PP + gy * 44 + gx];
      }
    }
    #pragma unroll
    for (int s = 0; s < NW; ++s) {
      int e = tid + s * 256;
      if (e < NWF4) {
        int k = e >> 4, c4 = (e & 15) * 4;
        wr[s] = *(const float4*)&wtd[(size_t)(ci0 * 9 + k) * CO + co0 + c4];
      }
    }
  };
  auto stage_store = [&]() {
    #pragma unroll
    for (int s = 0; s < NX; ++s) {
      int e = tid + s * 256;
      if (e < NXE) xs[e] = xr[s];
    }
    #pragma unroll
    for (int s = 0; s < NW; ++s) {
      int e = tid + s * 256;
      if (e < NWF4) {
        int k = e >> 4, c4 = (e & 15) * 4;
        *(float4*)&wls[k * 68 + c4] = wr[s];
      }
    }
  };

  stage_load(0);
  for (int ci0 = 0; ci0 < CINC; ci0 += 4) {
    __syncthreads();
    stage_store();
    __syncthreads();
    if (ci0 + 4 < CINC) stage_load(ci0 + 4);
    #pragma unroll
    for (int ci = 0; ci < 4; ++ci) {
      const float* xc = xs + ci * EE;
      #pragma unroll
      for (int kh = 0; kh < 3; ++kh) {
        const float* xrow = xc + (py + DIL * kh) * EXT + px0;
        #pragma unroll
        for (int kw = 0; kw < 3; ++kw) {
          const float* xq = xrow + DIL * kw;
          float4 xv = make_float4(xq[0], xq[1], xq[2], xq[3]);
          const float4 w0 = *(const float4*)&wls[(ci * 9 + kh * 3 + kw) * 68 + co_sub];
          FMAQ(acc, w0, xv)
        }
      }
    }
  }

  const int gy = ty0 + py, gx0 = tx0 + px0;
  if (gy < 44 && gx0 < 44) {
    #pragma unroll
    for (int a = 0; a < 4; ++a) {
      const int co = co0 + co_sub + a;
      const float bv = bia[co];
      *(float4*)&outbase[(size_t)co * PP + gy * 44 + gx0] =
          make_float4(acc[a][0] + bv, acc[a][1] + bv,
                      acc[a][2] + bv, acc[a][3] + bv);
    }
  }
}

__global__ __launch_bounds__(256) void k_conv(
    const float* __restrict__ x, const float* __restrict__ wt,
    const float* __restrict__ b3, const float* __restrict__ b5,
    const float* __restrict__ b7, float* __restrict__ conv_out)
{
  __shared__ alignas(16) float xs[4 * 484];
  __shared__ alignas(16) float wls[36 * 68];
  const int zt = blockIdx.z, di = zt >> 1, b = zt & 1;
  const int pt = blockIdx.x;
  const int ty0 = (pt / 6) * 8, tx0 = (pt % 6) * 8;
  const int co0 = blockIdx.y * 64;
  const float* xb  = x + (size_t)b * CINC * PP;
  const float* wtd = wt + (size_t)di * KCONV * CO;
  const float* bia = (di == 0) ? b3 : (di == 1 ? b5 : b7);
  float* outbase = conv_out + (size_t)(di * NB + b) * CO * PP;
  if (di == 0)      conv_body<3>(xs, wls, xb, wtd, bia, outbase, ty0, tx0, co0);
  else if (di == 1) conv_body<5>(xs, wls, xb, wtd, bia, outbase, ty0, tx0, co0);
  else              conv_body<7>(xs, wls, xb, wtd, bia, outbase, ty0, tx0, co0);
}

// ======================================================================
// K2: qk projection (fp32 compute). Writes fp32 q (scaled), bf16 q and k.
// ======================================================================
__global__ __launch_bounds__(256) void k_qk(
    const float* __restrict__ x, const float* __restrict__ conv,
    const float* __restrict__ wqk,
    float* __restrict__ qbuf, ushort* __restrict__ qbf, ushort* __restrict__ kbf)
{
  const int b = blockIdx.z;
  const int o0 = blockIdx.y * 128, p0 = blockIdx.x * 128;
  __shared__ alignas(16) float als[8 * 132];
  __shared__ alignas(16) float bls[8 * 132];
  const int tid = threadIdx.x;
  const int os4 = (tid & 15) * 4, ps4 = (tid >> 4) * 4;
  float acc[2][2][4][4];
  #pragma unroll
  for (int i = 0; i < 2; ++i)
    #pragma unroll
    for (int j = 0; j < 2; ++j)
      #pragma unroll
      for (int a = 0; a < 4; ++a)
        #pragma unroll
        for (int p = 0; p < 4; ++p) acc[i][j][a][p] = 0.f;

  const int aoo = tid >> 1, add = (tid & 1) * 4;
  const int bcc = tid >> 5;
  const int bp  = p0 + (tid & 31) * 4;
  const float* aptr = wqk + (size_t)(o0 + aoo) * FCH + add;

  for (int k0 = 0; k0 < FCH; k0 += 8) {
    float4 av = *(const float4*)(aptr + k0);
    float4 bv = make_float4(0.f, 0.f, 0.f, 0.f);
    {
      int c = k0 + bcc;
      if (bp < PP) {
        const float* src;
        if (c < CINC) src = x + ((size_t)b * CINC + c) * PP;
        else {
          int c2 = c - CINC; int dd2 = c2 / CO, cc2 = c2 - dd2 * CO;
          src = conv + ((size_t)(dd2 * NB + b) * CO + cc2) * PP;
        }
        bv = *(const float4*)(src + bp);
      }
    }
    __syncthreads();
    als[(add + 0) * 132 + aoo] = av.x;
    als[(add + 1) * 132 + aoo] = av.y;
    als[(add + 2) * 132 + aoo] = av.z;
    als[(add + 3) * 132 + aoo] = av.w;
    *(float4*)&bls[bcc * 132 + (tid & 31) * 4] = bv;
    __syncthreads();
    #pragma unroll
    for (int kk = 0; kk < 8; ++kk) {
      const float4 a0 = *(const float4*)&als[kk * 132 + os4];
      const float4 a1 = *(const float4*)&als[kk * 132 + os4 + 64];
      const float4 b0 = *(const float4*)&bls[kk * 132 + ps4];
      const float4 b1 = *(const float4*)&bls[kk * 132 + ps4 + 64];
      FMAQ(acc[0][0], a0, b0) FMAQ(acc[0][1], a0, b1)
      FMAQ(acc[1][0], a1, b0) FMAQ(acc[1][1], a1, b1)
    }
  }
  #pragma unroll
  for (int oq = 0; oq < 2; ++oq)
    #pragma unroll
    for (int a = 0; a < 4; ++a) {
      const int o = o0 + os4 + oq * 64 + a;
      const bool isq = (o < CINC);
      const int oo = isq ? o : o - CINC;
      const int hd = oo / DH, dd = oo - hd * DH;
      const size_t rowb = (size_t)(b * NHD + hd) * PP;
      const float s = isq ? 0.5f : 1.0f;      // HEAD^-0.5 = 0.5
      #pragma unroll
      for (int pq = 0; pq < 2; ++pq)
        #pragma unroll
        for (int pi = 0; pi < 4; ++pi) {
          int pp = p0 + ps4 + pq * 64 + pi;
          if (pp < PP) {
            float fv = acc[oq][pq][a][pi] * s;
            if (isq) {
              qbuf[(rowb + pp) * DH + dd] = fv;
              qbf [(rowb + pp) * DH + dd] = f2bf(fv);
            } else {
              kbf [(rowb + pp) * DH + dd] = f2bf(fv);
            }
          }
        }
    }
}

// ======================================================================
// K3: rel-pos dot products (fp32 q).
// ======================================================================
__global__ __launch_bounds__(128) void k_qrel(
    const float* __restrict__ qbuf, const float* __restrict__ relh,
    const float* __restrict__ relw,
    float* __restrict__ qrh, float* __restrict__ qrw)
{
  const int bh = blockIdx.x / PP, pos = blockIdx.x % PP;
  const int xr = pos / 44, yc = pos - 44 * xr;
  __shared__ alignas(16) float qs[192];
  const int tid = threadIdx.x;
  for (int e = tid; e < 192; e += 128)
    qs[e] = qbuf[((size_t)bh * PP + pos) * DH + e];
  __syncthreads();
  const float4* q4 = (const float4*)qs;
  if (tid < 44) {
    const float4* r4 = (const float4*)&relh[(size_t)(tid - xr + 99) * DH];
    float s = 0.f;
    #pragma unroll
    for (int d = 0; d < 48; ++d) {
      float4 a = q4[d], bb = r4[d];
      s += a.x * bb.x + a.y * bb.y + a.z * bb.z + a.w * bb.w;
    }
    qrh[((size_t)bh * PP + pos) * 44 + tid] = s;
  } else if (tid >= 64 && tid < 108) {
    const int v = tid - 64;
    const float4* r4 = (const float4*)&relw[(size_t)(v - yc + 99) * DH];
    float s = 0.f;
    #pragma unroll
    for (int d = 0; d < 48; ++d) {
      float4 a = q4[d], bb = r4[d];
      s += a.x * bb.x + a.y * bb.y + a.z * bb.z + a.w * bb.w;
    }
    qrw[((size_t)bh * PP + pos) * 44 + v] = s;
  }
}

// ======================================================================
// K4: v projection -> channel-major vchan[b][768][1936] (fp32).
// ======================================================================
__global__ __launch_bounds__(256) void k_v(
    const float* __restrict__ x, const float* __restrict__ wv,
    float* __restrict__ vchan)
{
  const int b = blockIdx.z;
  const int o0 = blockIdx.y * 128, p0 = blockIdx.x * 128;
  __shared__ alignas(16) float als[8 * 132];
  __shared__ alignas(16) float bls[8 * 132];
  const int tid = threadIdx.x;
  const int os4 = (tid & 15) * 4, ps4 = (tid >> 4) * 4;
  float acc[2][2][4][4];
  #pragma unroll
  for (int i = 0; i < 2; ++i)
    #pragma unroll
    for (int j = 0; j < 2; ++j)
      #pragma unroll
      for (int a = 0; a < 4; ++a)
        #pragma unroll
        for (int p = 0; p < 4; ++p) acc[i][j][a][p] = 0.f;

  const int aoo = tid >> 1, add = (tid & 1) * 4;
  const int bcc = tid >> 5;
  const int bp  = p0 + (tid & 31) * 4;
  const float* aptr = wv + (size_t)(o0 + aoo) * CINC + add;

  for (int k0 = 0; k0 < CINC; k0 += 8) {
    float4 av = *(const float4*)(aptr + k0);
    float4 bv = (bp < PP)
        ? *(const float4*)&x[((size_t)b * CINC + k0 + bcc) * PP + bp]
        : make_float4(0.f, 0.f, 0.f, 0.f);
    __syncthreads();
    als[(add + 0) * 132 + aoo] = av.x;
    als[(add + 1) * 132 + aoo] = av.y;
    als[(add + 2) * 132 + aoo] = av.z;
    als[(add + 3) * 132 + aoo] = av.w;
    *(float4*)&bls[bcc * 132 + (tid & 31) * 4] = bv;
    __syncthreads();
    #pragma unroll
    for (int kk = 0; kk < 8; ++kk) {
      const float4 a0 = *(const float4*)&als[kk * 132 + os4];
      const float4 a1 = *(const float4*)&als[kk * 132 + os4 + 64];
      const float4 b0 = *(const float4*)&bls[kk * 132 + ps4];
      const float4 b1 = *(const float4*)&bls[kk * 132 + ps4 + 64];
      FMAQ(acc[0][0], a0, b0) FMAQ(acc[0][1], a0, b1)
      FMAQ(acc[1][0], a1, b0) FMAQ(acc[1][1], a1, b1)
    }
  }
  #pragma unroll
  for (int oq = 0; oq < 2; ++oq)
    #pragma unroll
    for (int a = 0; a < 4; ++a) {
      const int o = o0 + os4 + oq * 64 + a;
      float* row = vchan + ((size_t)b * CINC + o) * PP;
      #pragma unroll
      for (int pq = 0; pq < 2; ++pq) {
        int p = p0 + ps4 + pq * 64;
        if (p < PP)
          *(float4*)&row[p] = make_float4(acc[oq][pq][a][0], acc[oq][pq][a][1],
                                          acc[oq][pq][a][2], acc[oq][pq][a][3]);
      }
    }
}

// ======================================================================
// K5: MFMA QK^T. 128i x 128j block, 4 waves (2x2), 64x64 per wave.
// A = q rows (bf16), B = k cols (bf16), C += rel terms, fp32 out.
// ======================================================================
__global__ __launch_bounds__(256) void k_sim(
    const ushort* __restrict__ qbf, const ushort* __restrict__ kbf,
    const float* __restrict__ qrh, const float* __restrict__ qrw,
    float* __restrict__ sim, int bh0)
{
  const int z = blockIdx.z, bh = bh0 + z;
  const size_t base = (size_t)bh * PP;
  const size_t sbase = (size_t)z * PP;
  const int i0 = blockIdx.y * 128, j0 = blockIdx.x * 128;
  __shared__ ushort qls[128][40];
  __shared__ ushort kls[128][40];
  const int tid = threadIdx.x, lane = tid & 63, wv = tid >> 6;
  const int wi = wv >> 1, wj = wv & 1;
  const int fr = lane & 15, fk = (lane >> 4) * 8, crw = (lane >> 4) * 4;
  const int srow = tid >> 1, scol = (tid & 1) * 16;

  const f32x4 zf = {0.f, 0.f, 0.f, 0.f};
  f32x4 acc[4][4];
  #pragma unroll
  for (int rt = 0; rt < 4; ++rt)
    #pragma unroll
    for (int ct = 0; ct < 4; ++ct) acc[rt][ct] = zf;

  for (int d0 = 0; d0 < DH; d0 += 32) {
    uint4 qa = make_uint4(0,0,0,0), qb = qa, ka = qa, kb2 = qa;
    {
      int qi = i0 + srow;
      if (qi < PP) {
        const ushort* s = &qbf[(base + qi) * DH + d0 + scol];
        qa = *(const uint4*)s; qb = *(const uint4*)(s + 8);
      }
      int kj = j0 + srow;
      if (kj < PP) {
        const ushort* s = &kbf[(base + kj) * DH + d0 + scol];
        ka = *(const uint4*)s; kb2 = *(const uint4*)(s + 8);
      }
    }
    __syncthreads();
    *(uint4*)&qls[srow][scol] = qa;  *(uint4*)&qls[srow][scol + 8] = qb;
    *(uint4*)&kls[srow][scol] = ka;  *(uint4*)&kls[srow][scol + 8] = kb2;
    __syncthreads();
    short8v aq[4], bk[4];
    #pragma unroll
    for (int rt = 0; rt < 4; ++rt)
      aq[rt] = *(const short8v*)&qls[wi * 64 + rt * 16 + fr][fk];
    #pragma unroll
    for (int ct = 0; ct < 4; ++ct)
      bk[ct] = *(const short8v*)&kls[wj * 64 + ct * 16 + fr][fk];
    #pragma unroll
    for (int rt = 0; rt < 4; ++rt)
      #pragma unroll
      for (int ct = 0; ct < 4; ++ct)
        acc[rt][ct] = __builtin_amdgcn_mfma_f32_16x16x32_bf16(
            aq[rt], bk[ct], acc[rt][ct], 0, 0, 0);
  }

  #pragma unroll
  for (int ct = 0; ct < 4; ++ct) {
    const int j = j0 + wj * 64 + ct * 16 + fr;
    if (j >= PP) continue;
    const int u = j / 44, v = j - 44 * u;
    #pragma unroll
    for (int rt = 0; rt < 4; ++rt) {
      const int ib = i0 + wi * 64 + rt * 16 + crw;
      #pragma unroll
      for (int r = 0; r < 4; ++r) {
        const int i = ib + r;
        if (i < PP)
          sim[(sbase + i) * PP + j] =
              acc[rt][ct][r] + qrh[(base + i) * 44 + u] + qrw[(base + i) * 44 + v];
      }
    }
  }
}

// ======================================================================
// K6: row softmax: fp32 exp into sim, bf16 copy into pbf (PPAD stride),
// rowsum into rsum. Normalization folded into PV epilogue.
// ======================================================================
__global__ __launch_bounds__(256) void k_softmax(
    float* __restrict__ sim, ushort* __restrict__ pbf,
    float* __restrict__ rsum, int row0)
{
  const size_t row = blockIdx.x;
  float4* p = (float4*)(sim + row * PP);
  ushort* pb = pbf + row * PPAD;
  const int tid = threadIdx.x;
  __shared__ float sred[4];

  float4 v0 = p[tid];
  float mx = fmaxf(fmaxf(v0.x, v0.y), fmaxf(v0.z, v0.w));
  const bool has2 = (tid + 256) < 484;
  float4 v1 = make_float4(0.f, 0.f, 0.f, 0.f);
  if (has2) {
    v1 = p[tid + 256];
    mx = fmaxf(mx, fmaxf(fmaxf(v1.x, v1.y), fmaxf(v1.z, v1.w)));
  }
  #pragma unroll
  for (int o = 32; o; o >>= 1) mx = fmaxf(mx, __shfl_xor(mx, o));
  if ((tid & 63) == 0) sred[tid >> 6] = mx;
  __syncthreads();
  mx = fmaxf(fmaxf(sred[0], sred[1]), fmaxf(sred[2], sred[3]));

  float sum;
  v0.x = __expf(v0.x - mx); v0.y = __expf(v0.y - mx);
  v0.z = __expf(v0.z - mx); v0.w = __expf(v0.w - mx);
  sum = v0.x + v0.y + v0.z + v0.w;
  p[tid] = v0;
  {
    unsigned lo = (unsigned)f2bf(v0.x) | ((unsigned)f2bf(v0.y) << 16);
    unsigned hi = (unsigned)f2bf(v0.z) | ((unsigned)f2bf(v0.w) << 16);
    *(uint2*)&pb[tid * 4] = make_uint2(lo, hi);
  }
  if (has2) {
    v1.x = __expf(v1.x - mx); v1.y = __expf(v1.y - mx);
    v1.z = __expf(v1.z - mx); v1.w = __expf(v1.w - mx);
    sum += v1.x + v1.y + v1.z + v1.w;
    p[tid + 256] = v1;
    unsigned lo = (unsigned)f2bf(v1.x) | ((unsigned)f2bf(v1.y) << 16);
    unsigned hi = (unsigned)f2bf(v1.z) | ((unsigned)f2bf(v1.w) << 16);
    *(uint2*)&pb[(tid + 256) * 4] = make_uint2(lo, hi);
  }
  if (tid < 2) *(uint4*)&pb[1936 + tid * 8] = make_uint4(0, 0, 0, 0);  // zero pad tail
  #pragma unroll
  for (int o = 32; o; o >>= 1) sum += __shfl_xor(sum, o);
  __syncthreads();
  if ((tid & 63) == 0) sred[tid >> 6] = sum;
  __syncthreads();
  if (tid == 0) rsum[row0 + row] = sred[0] + sred[1] + sred[2] + sred[3];
}

// ======================================================================
// K7: MFMA PV. 128i x 64d block, 4 waves (2x2), 64i x 32d per wave.
// A = P rows (bf16, PPAD-padded), B = V from fp32 vchan (convert in stage).
// Output pos-major obuf[bh][i][192], 1/rsum folded in.
// ======================================================================
__global__ __launch_bounds__(256) void k_pv(
    const ushort* __restrict__ pbf, const float* __restrict__ vchan,
    const float* __restrict__ rsum, float* __restrict__ obuf, int bh0)
{
  const int z = blockIdx.z, bh = bh0 + z, b = bh >> 2, hd = bh & 3;
  const size_t rbase = (size_t)bh * PP;
  const int i0 = blockIdx.y * 128, d0 = blockIdx.x * 64;
  __shared__ ushort pls[128][40];
  __shared__ ushort vls[64][40];
  const int tid = threadIdx.x, lane = tid & 63, wv = tid >> 6;
  const int wi = wv >> 1, wj = wv & 1;
  const int fr = lane & 15, fk = (lane >> 4) * 8, crw = (lane >> 4) * 4;
  const int srow = tid >> 1, scol = (tid & 1) * 16;   // P staging
  const int vdd = tid >> 2, vjj = (tid & 3) * 8;      // V staging
  const size_t vrow = ((size_t)b * CINC + hd * DH + d0 + vdd) * PP;

  const f32x4 zf = {0.f, 0.f, 0.f, 0.f};
  f32x4 acc[4][2];
  #pragma unroll
  for (int rt = 0; rt < 4; ++rt)
    #pragma unroll
    for (int ct = 0; ct < 2; ++ct) acc[rt][ct] = zf;

  for (int k0 = 0; k0 < PPAD; k0 += 32) {
    uint4 pa_ = make_uint4(0,0,0,0), pb_ = pa_;
    {
      int pi = i0 + srow;
      if (pi < PP) {
        const ushort* s = &pbf[((size_t)z * PP + pi) * PPAD + k0 + scol];
        pa_ = *(const uint4*)s; pb_ = *(const uint4*)(s + 8);
      }
    }
    float4 va = make_float4(0.f,0.f,0.f,0.f), vb2 = va;
    if (k0 + vjj < PP) {
      va  = *(const float4*)&vchan[vrow + k0 + vjj];
      vb2 = *(const float4*)&vchan[vrow + k0 + vjj + 4];
    }
    __syncthreads();
    *(uint4*)&pls[srow][scol] = pa_;  *(uint4*)&pls[srow][scol + 8] = pb_;
    {
      uint4 vp;
      vp.x = (unsigned)f2bf(va.x)  | ((unsigned)f2bf(va.y)  << 16);
      vp.y = (unsigned)f2bf(va.z)  | ((unsigned)f2bf(va.w)  << 16);
      vp.z = (unsigned)f2bf(vb2.x) | ((unsigned)f2bf(vb2.y) << 16);
      vp.w = (unsigned)f2bf(vb2.z) | ((unsigned)f2bf(vb2.w) << 16);
      *(uint4*)&vls[vdd][vjj] = vp;
    }
    __syncthreads();
    short8v ap[4], bv[2];
    #pragma unroll
    for (int rt = 0; rt < 4; ++rt)
      ap[rt] = *(const short8v*)&pls[wi * 64 + rt * 16 + fr][fk];
    #pragma unroll
    for (int ct = 0; ct < 2; ++ct)
      bv[ct] = *(const short8v*)&vls[wj * 32 + ct * 16 + fr][fk];
    #pragma unroll
    for (int rt = 0; rt < 4; ++rt)
      #pragma unroll
      for (int ct = 0; ct < 2; ++ct)
        acc[rt][ct] = __builtin_amdgcn_mfma_f32_16x16x32_bf16(
            ap[rt], bv[ct], acc[rt][ct], 0, 0, 0);
  }

  #pragma unroll
  for (int rt = 0; rt < 4; ++rt) {
    const int ib = i0 + wi * 64 + rt * 16 + crw;
    #pragma unroll
    for (int r = 0; r < 4; ++r) {
      const int i = ib + r;
      if (i >= PP) continue;
      const float inv = 1.f / rsum[rbase + i];
      #pragma unroll
      for (int ct = 0; ct < 2; ++ct) {
        const int d = d0 + wj * 32 + ct * 16 + fr;
        obuf[(rbase + i) * DH + d] = acc[rt][ct][r] * inv;
      }
    }
  }
}

// ======================================================================
// K8: output projection + residual (fp32). B gathered from pos-major obuf.
// ======================================================================
__global__ __launch_bounds__(256) void k_out(
    const float* __restrict__ x, const float* __restrict__ obuf,
    const float* __restrict__ wproj, const float* __restrict__ gamma,
    float* __restrict__ out)
{
  const int b = blockIdx.z;
  const int o0 = blockIdx.y * 128, p0 = blockIdx.x * 128;
  __shared__ alignas(16) float als[8 * 132];
  __shared__ alignas(16) float bls[8 * 132];
  const int tid = threadIdx.x;
  const int os4 = (tid & 15) * 4, ps4 = (tid >> 4) * 4;
  float acc[2][2][4][4];
  #pragma unroll
  for (int i = 0; i < 2; ++i)
    #pragma unroll
    for (int j = 0; j < 2; ++j)
      #pragma unroll
      for (int a = 0; a < 4; ++a)
        #pragma unroll
        for (int p = 0; p < 4; ++p) acc[i][j][a][p] = 0.f;

  const int aoo = tid >> 1, add = (tid & 1) * 4;
  const int bpl = tid >> 1, bc4 = (tid & 1) * 4;     // B: 128 p x {0,4} c-offset
  const float* aptr = wproj + (size_t)(o0 + aoo) * CINC + add;

  for (int c0 = 0; c0 < CINC; c0 += 8) {
    float4 av = *(const float4*)(aptr + c0);
    const int hd = c0 / DH, cb = c0 - hd * DH;       // 8 | 192: chunk within one head
    float4 bv = make_float4(0.f, 0.f, 0.f, 0.f);
    {
      int p = p0 + bpl;
      if (p < PP)
        bv = *(const float4*)&obuf[((size_t)(b * NHD + hd) * PP + p) * DH + cb + bc4];
    }
    __syncthreads();
    als[(add + 0) * 132 + aoo] = av.x;
    als[(add + 1) * 132 + aoo] = av.y;
    als[(add + 2) * 132 + aoo] = av.z;
    als[(add + 3) * 132 + aoo] = av.w;
    bls[(bc4 + 0) * 132 + bpl] = bv.x;
    bls[(bc4 + 1) * 132 + bpl] = bv.y;
    bls[(bc4 + 2) * 132 + bpl] = bv.z;
    bls[(bc4 + 3) * 132 + bpl] = bv.w;
    __syncthreads();
    #pragma unroll
    for (int kk = 0; kk < 8; ++kk) {
      const float4 a0 = *(const float4*)&als[kk * 132 + os4];
      const float4 a1 = *(const float4*)&als[kk * 132 + os4 + 64];
      const float4 b0 = *(const float4*)&bls[kk * 132 + ps4];
      const float4 b1 = *(const float4*)&bls[kk * 132 + ps4 + 64];
      FMAQ(acc[0][0], a0, b0) FMAQ(acc[0][1], a0, b1)
      FMAQ(acc[1][0], a1, b0) FMAQ(acc[1][1], a1, b1)
    }
  }
  const float g = gamma[0];
  #pragma unroll
  for (int oq = 0; oq < 2; ++oq)
    #pragma unroll
    for (int a = 0; a < 4; ++a) {
      const int o = o0 + os4 + oq * 64 + a;
      const float* xr = &x[((size_t)b * CINC + o) * PP];
      float* dst = &out[((size_t)b * CINC + o) * PP];
      #pragma unroll
      for (int pq = 0; pq < 2; ++pq) {
        int p = p0 + ps4 + pq * 64;
        if (p < PP) {
          float4 xv = *(const float4*)&xr[p];
          *(float4*)&dst[p] = make_float4(xv.x + g * acc[oq][pq][a][0],
                                          xv.y + g * acc[oq][pq][a][1],
                                          xv.z + g * acc[oq][pq][a][2],
                                          xv.w + g * acc[oq][pq][a][3]);
        }
      }
    }
}

// ======================================================================
extern "C" void kernel_launch(void* const* d_in, const int* in_sizes, int n_in,
                              void* d_out, int out_size, void* d_ws, size_t ws_size,
                              hipStream_t stream)
{
  const float* x    = (const float*)d_in[0];
  const float* w3   = (const float*)d_in[1];
  const float* b3   = (const float*)d_in[2];
  const float* w5   = (const float*)d_in[3];
  const float* b5   = (const float*)d_in[4];
  const float* w7   = (const float*)d_in[5];
  const float* b7   = (const float*)d_in[6];
  const float* wqk  = (const float*)d_in[7];
  const float* relh = (const float*)d_in[8];
  const float* relw = (const float*)d_in[9];
  const float* wv   = (const float*)d_in[10];
  const float* wpr  = (const float*)d_in[11];
  const float* gam  = (const float*)d_in[12];
  float* out = (float*)d_out;
  float* ws  = (float*)d_ws;

  float* conv = ws + OFF_CONV;
  float* qb   = ws + OFF_Q;
  ushort* qbf = (ushort*)(ws + OFF_K);         // bf16 q
  ushort* kbf = qbf + N_QKV;                   // bf16 k (same region as old fp32 k)
  float* vch  = ws + OFF_V;
  float* obuf = ws + OFF_O;
  float* qrh  = ws + OFF_QRH;
  float* qrw  = ws + OFF_QRW;
  float* rs   = ws + OFF_RS;
  float* wt   = ws + OFF_WT;
  float* sim  = ws + OFF_SIM;

  // Largest bh-group whose fp32 sim slab + bf16 P slab fit the workspace.
  int g = 8;
  while (g > 1 &&
         (OFF_SIM + (size_t)g * SIM_BH) * sizeof(float) +
         (size_t)g * PP * PPAD * sizeof(ushort) > ws_size) g >>= 1;
  ushort* pbf = (ushort*)(ws + OFF_SIM + (size_t)g * SIM_BH);

  k_wt<<<dim3(108, 6, 3), 256, 0, stream>>>(w3, w5, w7, wt);
  k_conv<<<dim3(36, 6, 6), 256, 0, stream>>>(x, wt, b3, b5, b7, conv);
  k_qk<<<dim3(16, 12, 2), 256, 0, stream>>>(x, conv, wqk, qb, qbf, kbf);
  k_qrel<<<dim3(NB * NHD * PP), 128, 0, stream>>>(qb, relh, relw, qrh, qrw);
  k_v<<<dim3(16, 6, 2), 256, 0, stream>>>(x, wv, vch);

  for (int bh0 = 0; bh0 < NB * NHD; bh0 += g) {
    k_sim<<<dim3(16, 16, g), 256, 0, stream>>>(qbf, kbf, qrh, qrw, sim, bh0);
    k_softmax<<<dim3(g * PP), 256, 0, stream>>>(sim, pbf, rs, bh0 * PP);
    k_pv<<<dim3(3, 16, g), 256, 0, stream>>>(pbf, vch, rs, obuf, bh0);
  }
  k_out<<<dim3(16, 6, 2), 256, 0, stream>>>(x, obuf, wpr, gam, out);
}

// Round 9
// 1450.773 us; speedup vs baseline: 3.4423x; 1.7365x over previous
//
#include <hip/hip_runtime.h>
#include <hip/hip_bf16.h>
#include <cstdint>
#include <cstddef>

// ---------------- problem constants ----------------
#define NB   2
#define CINC 768
#define PP   1936          // 44*44
#define CO   384
#define NHD  4
#define DH   192
#define FCH  1920          // 768 + 3*384
#define KCONV 6912         // 768*9
#define PPAD 1952          // PP padded to 61*32 (bf16 P row stride)

typedef __attribute__((ext_vector_type(8))) short short8v;   // 8 bf16
typedef __attribute__((ext_vector_type(4))) float f32x4;     // MFMA acc

__device__ __forceinline__ ushort f2bf(float f) {
  union { float f; unsigned u; } c; c.f = f;
  unsigned b = c.u;
  return (ushort)((b + 0x7FFFu + ((b >> 16) & 1u)) >> 16);   // RNE
}

// ---------------- workspace layout (floats) ----------------
static const size_t OFF_CONV = 0;
static const size_t N_CONV   = (size_t)3 * NB * CO * PP;       // 4,460,544
static const size_t OFF_Q    = OFF_CONV + N_CONV;
static const size_t N_QKV    = (size_t)NB * NHD * PP * DH;     // 2,973,696
static const size_t OFF_K    = OFF_Q + N_QKV;                  // region reused: qbf+kbf (bf16)
static const size_t OFF_V    = OFF_K + N_QKV;                  // vchan fp32 channel-major
static const size_t OFF_O    = OFF_V + N_QKV;                  // obuf fp32 [bh][pos][192]
static const size_t OFF_QRH  = OFF_O + N_QKV;
static const size_t N_QR     = (size_t)NB * NHD * PP * 44;     // 681,472
static const size_t OFF_QRW  = OFF_QRH + N_QR;
static const size_t OFF_RS   = OFF_QRW + N_QR;                 // 15,488 rowsums
static const size_t OFF_WT   = OFF_RS + (size_t)NB * NHD * PP; // bf16 conv weights (reuse old wt slot)
static const size_t N_WT     = (size_t)3 * KCONV * CO;         // 7,962,624 floats reserved
static const size_t OFF_SIM  = OFF_WT + N_WT;                  // slab: g*PP*PP fp32, then pbf bf16
static const size_t SIM_BH   = (size_t)PP * PP;                // 3,748,096 per bh

// rank-1 outer-product accumulate: ACC[r][c] += A[r]*B[c]
#define FMAQ(ACC, A, B) { \
  ACC[0][0]+=A.x*B.x; ACC[0][1]+=A.x*B.y; ACC[0][2]+=A.x*B.z; ACC[0][3]+=A.x*B.w; \
  ACC[1][0]+=A.y*B.x; ACC[1][1]+=A.y*B.y; ACC[1][2]+=A.y*B.z; ACC[1][3]+=A.y*B.w; \
  ACC[2][0]+=A.z*B.x; ACC[2][1]+=A.z*B.y; ACC[2][2]+=A.z*B.z; ACC[2][3]+=A.z*B.w; \
  ACC[3][0]+=A.w*B.x; ACC[3][1]+=A.w*B.y; ACC[3][2]+=A.w*B.z; ACC[3][3]+=A.w*B.w; }

// ======================================================================
// K0: weight fp32 -> bf16 copy: wbf[di][co][k], contiguous, coalesced.
// grid (1296, 3): per di, 2,654,208 elems = 1296 blocks * 256 thr * 8.
// ======================================================================
__global__ __launch_bounds__(256) void k_wbf(
    const float* __restrict__ w3, const float* __restrict__ w5,
    const float* __restrict__ w7, ushort* __restrict__ wbf)
{
  const int di = blockIdx.y;
  const float* __restrict__ w = (di == 0) ? w3 : (di == 1 ? w5 : w7);
  ushort* __restrict__ dst = wbf + (size_t)di * CO * KCONV;
  const size_t off = ((size_t)blockIdx.x * 256 + threadIdx.x) * 8;
  float4 f0 = *(const float4*)&w[off];
  float4 f1 = *(const float4*)&w[off + 4];
  uint4 pk;
  pk.x = (unsigned)f2bf(f0.x) | ((unsigned)f2bf(f0.y) << 16);
  pk.y = (unsigned)f2bf(f0.z) | ((unsigned)f2bf(f0.w) << 16);
  pk.z = (unsigned)f2bf(f1.x) | ((unsigned)f2bf(f1.y) << 16);
  pk.w = (unsigned)f2bf(f1.z) | ((unsigned)f2bf(f1.w) << 16);
  *(uint4*)&dst[off] = pk;
}

// ======================================================================
// K1 v4: dilated convs as implicit-GEMM MFMA.
// out[co][pos] = sum_k w[co][k] * im2col(x)[pos][k], K = 6912.
// Block: 192co x 64pos, 4 waves (2x2): wave = 96co x 32pos,
// acc[6][2] f32x4. B-tile (64pos x 32k) built per chunk by in-LDS
// im2col gather from x; A-tile copied from bf16 wbf.
// grid (31 pos-tiles, 2 co-tiles, 6 di*b), block 256.
// ======================================================================
__global__ __launch_bounds__(256) void k_conv(
    const float* __restrict__ x, const ushort* __restrict__ wbf,
    const float* __restrict__ b3, const float* __restrict__ b5,
    const float* __restrict__ b7, float* __restrict__ conv_out)
{
  __shared__ ushort als[192][40];
  __shared__ ushort bls[64][40];
  const int z = blockIdx.z, di = z >> 1, b = z & 1;
  const int dil = 3 + 2 * di;
  const ushort* __restrict__ wd = wbf + (size_t)di * CO * KCONV;
  const float* __restrict__ bia = (di == 0) ? b3 : (di == 1 ? b5 : b7);
  const float* __restrict__ xb = x + (size_t)b * CINC * PP;
  const int p0 = blockIdx.x * 64;
  const int co0 = blockIdx.y * 192;
  const int tid = threadIdx.x, lane = tid & 63, wv = tid >> 6;
  const int wi = wv >> 1, wj = wv & 1;
  const int fr = lane & 15, fk = (lane >> 4) * 8, crw = (lane >> 4) * 4;

  // A staging: 3 rounds x (64co x 32k / round); 8 bf16 per thread/round.
  const int aco = tid >> 2, akf = (tid & 3) * 8;
  // B staging: one pos row, 8 consecutive k per thread.
  const int bpos_l = tid >> 2, bkk0 = (tid & 3) * 8;
  const int bpos = p0 + bpos_l;
  const unsigned ypos = (unsigned)bpos / 44u;
  const unsigned xpos = (unsigned)bpos - 44u * ypos;
  const bool bvalid = bpos < PP;

  const f32x4 zf = {0.f, 0.f, 0.f, 0.f};
  f32x4 acc[6][2];
  #pragma unroll
  for (int rt = 0; rt < 6; ++rt)
    #pragma unroll
    for (int ct = 0; ct < 2; ++ct) acc[rt][ct] = zf;

  for (int k0 = 0; k0 < KCONV; k0 += 32) {
    // B gather into registers (global loads overlap with barrier wait)
    ushort tmp[8];
    #pragma unroll
    for (int i = 0; i < 8; ++i) {
      const int k = k0 + bkk0 + i;
      const unsigned ci = (unsigned)k / 9u;
      const unsigned tap = (unsigned)k - 9u * ci;
      const unsigned kh = tap / 3u;
      const unsigned kw = tap - 3u * kh;
      const int gy = (int)ypos + dil * (int)kh - dil;
      const int gx = (int)xpos + dil * (int)kw - dil;
      float v = 0.f;
      if (bvalid && (unsigned)gy < 44u && (unsigned)gx < 44u)
        v = xb[(size_t)ci * PP + gy * 44 + gx];
      tmp[i] = f2bf(v);
    }
    __syncthreads();                 // previous chunk's frag reads done
    #pragma unroll
    for (int r = 0; r < 3; ++r) {    // A: bf16 tile copy
      const int co = r * 64 + aco;
      *(uint4*)&als[co][akf] =
          *(const uint4*)&wd[(size_t)(co0 + co) * KCONV + k0 + akf];
    }
    {
      uint4 pk;
      pk.x = (unsigned)tmp[0] | ((unsigned)tmp[1] << 16);
      pk.y = (unsigned)tmp[2] | ((unsigned)tmp[3] << 16);
      pk.z = (unsigned)tmp[4] | ((unsigned)tmp[5] << 16);
      pk.w = (unsigned)tmp[6] | ((unsigned)tmp[7] << 16);
      *(uint4*)&bls[bpos_l][bkk0] = pk;
    }
    __syncthreads();
    short8v af[6], bf_[2];
    #pragma unroll
    for (int rt = 0; rt < 6; ++rt)
      af[rt] = *(const short8v*)&als[wi * 96 + rt * 16 + fr][fk];
    #pragma unroll
    for (int ct = 0; ct < 2; ++ct)
      bf_[ct] = *(const short8v*)&bls[wj * 32 + ct * 16 + fr][fk];
    #pragma unroll
    for (int rt = 0; rt < 6; ++rt)
      #pragma unroll
      for (int ct = 0; ct < 2; ++ct)
        acc[rt][ct] = __builtin_amdgcn_mfma_f32_16x16x32_bf16(
            af[rt], bf_[ct], acc[rt][ct], 0, 0, 0);
  }

  float* __restrict__ outb = conv_out + (size_t)(di * NB + b) * CO * PP;
  #pragma unroll
  for (int rt = 0; rt < 6; ++rt) {
    #pragma unroll
    for (int r = 0; r < 4; ++r) {
      const int co = co0 + wi * 96 + rt * 16 + crw + r;
      const float bv = bia[co];
      #pragma unroll
      for (int ct = 0; ct < 2; ++ct) {
        const int pos = p0 + wj * 32 + ct * 16 + fr;
        if (pos < PP) outb[(size_t)co * PP + pos] = acc[rt][ct][r] + bv;
      }
    }
  }
}

// ======================================================================
// K2: qk projection (fp32 compute). Writes fp32 q (scaled), bf16 q and k.
// ======================================================================
__global__ __launch_bounds__(256) void k_qk(
    const float* __restrict__ x, const float* __restrict__ conv,
    const float* __restrict__ wqk,
    float* __restrict__ qbuf, ushort* __restrict__ qbf, ushort* __restrict__ kbf)
{
  const int b = blockIdx.z;
  const int o0 = blockIdx.y * 128, p0 = blockIdx.x * 128;
  __shared__ alignas(16) float als[8 * 132];
  __shared__ alignas(16) float bls[8 * 132];
  const int tid = threadIdx.x;
  const int os4 = (tid & 15) * 4, ps4 = (tid >> 4) * 4;
  float acc[2][2][4][4];
  #pragma unroll
  for (int i = 0; i < 2; ++i)
    #pragma unroll
    for (int j = 0; j < 2; ++j)
      #pragma unroll
      for (int a = 0; a < 4; ++a)
        #pragma unroll
        for (int p = 0; p < 4; ++p) acc[i][j][a][p] = 0.f;

  const int aoo = tid >> 1, add = (tid & 1) * 4;
  const int bcc = tid >> 5;
  const int bp  = p0 + (tid & 31) * 4;
  const float* aptr = wqk + (size_t)(o0 + aoo) * FCH + add;

  for (int k0 = 0; k0 < FCH; k0 += 8) {
    float4 av = *(const float4*)(aptr + k0);
    float4 bv = make_float4(0.f, 0.f, 0.f, 0.f);
    {
      int c = k0 + bcc;
      if (bp < PP) {
        const float* src;
        if (c < CINC) src = x + ((size_t)b * CINC + c) * PP;
        else {
          int c2 = c - CINC; int dd2 = c2 / CO, cc2 = c2 - dd2 * CO;
          src = conv + ((size_t)(dd2 * NB + b) * CO + cc2) * PP;
        }
        bv = *(const float4*)(src + bp);
      }
    }
    __syncthreads();
    als[(add + 0) * 132 + aoo] = av.x;
    als[(add + 1) * 132 + aoo] = av.y;
    als[(add + 2) * 132 + aoo] = av.z;
    als[(add + 3) * 132 + aoo] = av.w;
    *(float4*)&bls[bcc * 132 + (tid & 31) * 4] = bv;
    __syncthreads();
    #pragma unroll
    for (int kk = 0; kk < 8; ++kk) {
      const float4 a0 = *(const float4*)&als[kk * 132 + os4];
      const float4 a1 = *(const float4*)&als[kk * 132 + os4 + 64];
      const float4 b0 = *(const float4*)&bls[kk * 132 + ps4];
      const float4 b1 = *(const float4*)&bls[kk * 132 + ps4 + 64];
      FMAQ(acc[0][0], a0, b0) FMAQ(acc[0][1], a0, b1)
      FMAQ(acc[1][0], a1, b0) FMAQ(acc[1][1], a1, b1)
    }
  }
  #pragma unroll
  for (int oq = 0; oq < 2; ++oq)
    #pragma unroll
    for (int a = 0; a < 4; ++a) {
      const int o = o0 + os4 + oq * 64 + a;
      const bool isq = (o < CINC);
      const int oo = isq ? o : o - CINC;
      const int hd = oo / DH, dd = oo - hd * DH;
      const size_t rowb = (size_t)(b * NHD + hd) * PP;
      const float s = isq ? 0.5f : 1.0f;      // HEAD^-0.5 = 0.5
      #pragma unroll
      for (int pq = 0; pq < 2; ++pq)
        #pragma unroll
        for (int pi = 0; pi < 4; ++pi) {
          int pp = p0 + ps4 + pq * 64 + pi;
          if (pp < PP) {
            float fv = acc[oq][pq][a][pi] * s;
            if (isq) {
              qbuf[(rowb + pp) * DH + dd] = fv;
              qbf [(rowb + pp) * DH + dd] = f2bf(fv);
            } else {
              kbf [(rowb + pp) * DH + dd] = f2bf(fv);
            }
          }
        }
    }
}

// ======================================================================
// K3: rel-pos dot products (fp32 q).
// ======================================================================
__global__ __launch_bounds__(128) void k_qrel(
    const float* __restrict__ qbuf, const float* __restrict__ relh,
    const float* __restrict__ relw,
    float* __restrict__ qrh, float* __restrict__ qrw)
{
  const int bh = blockIdx.x / PP, pos = blockIdx.x % PP;
  const int xr = pos / 44, yc = pos - 44 * xr;
  __shared__ alignas(16) float qs[192];
  const int tid = threadIdx.x;
  for (int e = tid; e < 192; e += 128)
    qs[e] = qbuf[((size_t)bh * PP + pos) * DH + e];
  __syncthreads();
  const float4* q4 = (const float4*)qs;
  if (tid < 44) {
    const float4* r4 = (const float4*)&relh[(size_t)(tid - xr + 99) * DH];
    float s = 0.f;
    #pragma unroll
    for (int d = 0; d < 48; ++d) {
      float4 a = q4[d], bb = r4[d];
      s += a.x * bb.x + a.y * bb.y + a.z * bb.z + a.w * bb.w;
    }
    qrh[((size_t)bh * PP + pos) * 44 + tid] = s;
  } else if (tid >= 64 && tid < 108) {
    const int v = tid - 64;
    const float4* r4 = (const float4*)&relw[(size_t)(v - yc + 99) * DH];
    float s = 0.f;
    #pragma unroll
    for (int d = 0; d < 48; ++d) {
      float4 a = q4[d], bb = r4[d];
      s += a.x * bb.x + a.y * bb.y + a.z * bb.z + a.w * bb.w;
    }
    qrw[((size_t)bh * PP + pos) * 44 + v] = s;
  }
}

// ======================================================================
// K4: v projection -> channel-major vchan[b][768][1936] (fp32).
// ======================================================================
__global__ __launch_bounds__(256) void k_v(
    const float* __restrict__ x, const float* __restrict__ wv,
    float* __restrict__ vchan)
{
  const int b = blockIdx.z;
  const int o0 = blockIdx.y * 128, p0 = blockIdx.x * 128;
  __shared__ alignas(16) float als[8 * 132];
  __shared__ alignas(16) float bls[8 * 132];
  const int tid = threadIdx.x;
  const int os4 = (tid & 15) * 4, ps4 = (tid >> 4) * 4;
  float acc[2][2][4][4];
  #pragma unroll
  for (int i = 0; i < 2; ++i)
    #pragma unroll
    for (int j = 0; j < 2; ++j)
      #pragma unroll
      for (int a = 0; a < 4; ++a)
        #pragma unroll
        for (int p = 0; p < 4; ++p) acc[i][j][a][p] = 0.f;

  const int aoo = tid >> 1, add = (tid & 1) * 4;
  const int bcc = tid >> 5;
  const int bp  = p0 + (tid & 31) * 4;
  const float* aptr = wv + (size_t)(o0 + aoo) * CINC + add;

  for (int k0 = 0; k0 < CINC; k0 += 8) {
    float4 av = *(const float4*)(aptr + k0);
    float4 bv = (bp < PP)
        ? *(const float4*)&x[((size_t)b * CINC + k0 + bcc) * PP + bp]
        : make_float4(0.f, 0.f, 0.f, 0.f);
    __syncthreads();
    als[(add + 0) * 132 + aoo] = av.x;
    als[(add + 1) * 132 + aoo] = av.y;
    als[(add + 2) * 132 + aoo] = av.z;
    als[(add + 3) * 132 + aoo] = av.w;
    *(float4*)&bls[bcc * 132 + (tid & 31) * 4] = bv;
    __syncthreads();
    #pragma unroll
    for (int kk = 0; kk < 8; ++kk) {
      const float4 a0 = *(const float4*)&als[kk * 132 + os4];
      const float4 a1 = *(const float4*)&als[kk * 132 + os4 + 64];
      const float4 b0 = *(const float4*)&bls[kk * 132 + ps4];
      const float4 b1 = *(const float4*)&bls[kk * 132 + ps4 + 64];
      FMAQ(acc[0][0], a0, b0) FMAQ(acc[0][1], a0, b1)
      FMAQ(acc[1][0], a1, b0) FMAQ(acc[1][1], a1, b1)
    }
  }
  #pragma unroll
  for (int oq = 0; oq < 2; ++oq)
    #pragma unroll
    for (int a = 0; a < 4; ++a) {
      const int o = o0 + os4 + oq * 64 + a;
      float* row = vchan + ((size_t)b * CINC + o) * PP;
      #pragma unroll
      for (int pq = 0; pq < 2; ++pq) {
        int p = p0 + ps4 + pq * 64;
        if (p < PP)
          *(float4*)&row[p] = make_float4(acc[oq][pq][a][0], acc[oq][pq][a][1],
                                          acc[oq][pq][a][2], acc[oq][pq][a][3]);
      }
    }
}

// ======================================================================
// K5: MFMA QK^T. 128i x 128j block, 4 waves (2x2), 64x64 per wave.
// ======================================================================
__global__ __launch_bounds__(256) void k_sim(
    const ushort* __restrict__ qbf, const ushort* __restrict__ kbf,
    const float* __restrict__ qrh, const float* __restrict__ qrw,
    float* __restrict__ sim, int bh0)
{
  const int z = blockIdx.z, bh = bh0 + z;
  const size_t base = (size_t)bh * PP;
  const size_t sbase = (size_t)z * PP;
  const int i0 = blockIdx.y * 128, j0 = blockIdx.x * 128;
  __shared__ ushort qls[128][40];
  __shared__ ushort kls[128][40];
  const int tid = threadIdx.x, lane = tid & 63, wv = tid >> 6;
  const int wi = wv >> 1, wj = wv & 1;
  const int fr = lane & 15, fk = (lane >> 4) * 8, crw = (lane >> 4) * 4;
  const int srow = tid >> 1, scol = (tid & 1) * 16;

  const f32x4 zf = {0.f, 0.f, 0.f, 0.f};
  f32x4 acc[4][4];
  #pragma unroll
  for (int rt = 0; rt < 4; ++rt)
    #pragma unroll
    for (int ct = 0; ct < 4; ++ct) acc[rt][ct] = zf;

  for (int d0 = 0; d0 < DH; d0 += 32) {
    uint4 qa = make_uint4(0,0,0,0), qb = qa, ka = qa, kb2 = qa;
    {
      int qi = i0 + srow;
      if (qi < PP) {
        const ushort* s = &qbf[(base + qi) * DH + d0 + scol];
        qa = *(const uint4*)s; qb = *(const uint4*)(s + 8);
      }
      int kj = j0 + srow;
      if (kj < PP) {
        const ushort* s = &kbf[(base + kj) * DH + d0 + scol];
        ka = *(const uint4*)s; kb2 = *(const uint4*)(s + 8);
      }
    }
    __syncthreads();
    *(uint4*)&qls[srow][scol] = qa;  *(uint4*)&qls[srow][scol + 8] = qb;
    *(uint4*)&kls[srow][scol] = ka;  *(uint4*)&kls[srow][scol + 8] = kb2;
    __syncthreads();
    short8v aq[4], bk[4];
    #pragma unroll
    for (int rt = 0; rt < 4; ++rt)
      aq[rt] = *(const short8v*)&qls[wi * 64 + rt * 16 + fr][fk];
    #pragma unroll
    for (int ct = 0; ct < 4; ++ct)
      bk[ct] = *(const short8v*)&kls[wj * 64 + ct * 16 + fr][fk];
    #pragma unroll
    for (int rt = 0; rt < 4; ++rt)
      #pragma unroll
      for (int ct = 0; ct < 4; ++ct)
        acc[rt][ct] = __builtin_amdgcn_mfma_f32_16x16x32_bf16(
            aq[rt], bk[ct], acc[rt][ct], 0, 0, 0);
  }

  #pragma unroll
  for (int ct = 0; ct < 4; ++ct) {
    const int j = j0 + wj * 64 + ct * 16 + fr;
    if (j >= PP) continue;
    const int u = j / 44, v = j - 44 * u;
    #pragma unroll
    for (int rt = 0; rt < 4; ++rt) {
      const int ib = i0 + wi * 64 + rt * 16 + crw;
      #pragma unroll
      for (int r = 0; r < 4; ++r) {
        const int i = ib + r;
        if (i < PP)
          sim[(sbase + i) * PP + j] =
              acc[rt][ct][r] + qrh[(base + i) * 44 + u] + qrw[(base + i) * 44 + v];
      }
    }
  }
}

// ======================================================================
// K6: row softmax: fp32 exp into sim, bf16 copy into pbf (PPAD stride),
// rowsum into rsum.
// ======================================================================
__global__ __launch_bounds__(256) void k_softmax(
    float* __restrict__ sim, ushort* __restrict__ pbf,
    float* __restrict__ rsum, int row0)
{
  const size_t row = blockIdx.x;
  float4* p = (float4*)(sim + row * PP);
  ushort* pb = pbf + row * PPAD;
  const int tid = threadIdx.x;
  __shared__ float sred[4];

  float4 v0 = p[tid];
  float mx = fmaxf(fmaxf(v0.x, v0.y), fmaxf(v0.z, v0.w));
  const bool has2 = (tid + 256) < 484;
  float4 v1 = make_float4(0.f, 0.f, 0.f, 0.f);
  if (has2) {
    v1 = p[tid + 256];
    mx = fmaxf(mx, fmaxf(fmaxf(v1.x, v1.y), fmaxf(v1.z, v1.w)));
  }
  #pragma unroll
  for (int o = 32; o; o >>= 1) mx = fmaxf(mx, __shfl_xor(mx, o));
  if ((tid & 63) == 0) sred[tid >> 6] = mx;
  __syncthreads();
  mx = fmaxf(fmaxf(sred[0], sred[1]), fmaxf(sred[2], sred[3]));

  float sum;
  v0.x = __expf(v0.x - mx); v0.y = __expf(v0.y - mx);
  v0.z = __expf(v0.z - mx); v0.w = __expf(v0.w - mx);
  sum = v0.x + v0.y + v0.z + v0.w;
  p[tid] = v0;
  {
    unsigned lo = (unsigned)f2bf(v0.x) | ((unsigned)f2bf(v0.y) << 16);
    unsigned hi = (unsigned)f2bf(v0.z) | ((unsigned)f2bf(v0.w) << 16);
    *(uint2*)&pb[tid * 4] = make_uint2(lo, hi);
  }
  if (has2) {
    v1.x = __expf(v1.x - mx); v1.y = __expf(v1.y - mx);
    v1.z = __expf(v1.z - mx); v1.w = __expf(v1.w - mx);
    sum += v1.x + v1.y + v1.z + v1.w;
    p[tid + 256] = v1;
    unsigned lo = (unsigned)f2bf(v1.x) | ((unsigned)f2bf(v1.y) << 16);
    unsigned hi = (unsigned)f2bf(v1.z) | ((unsigned)f2bf(v1.w) << 16);
    *(uint2*)&pb[(tid + 256) * 4] = make_uint2(lo, hi);
  }
  if (tid < 2) *(uint4*)&pb[1936 + tid * 8] = make_uint4(0, 0, 0, 0);  // zero pad tail
  #pragma unroll
  for (int o = 32; o; o >>= 1) sum += __shfl_xor(sum, o);
  __syncthreads();
  if ((tid & 63) == 0) sred[tid >> 6] = sum;
  __syncthreads();
  if (tid == 0) rsum[row0 + row] = sred[0] + sred[1] + sred[2] + sred[3];
}

// ======================================================================
// K7: MFMA PV. 128i x 64d block, 4 waves (2x2), 64i x 32d per wave.
// ======================================================================
__global__ __launch_bounds__(256) void k_pv(
    const ushort* __restrict__ pbf, const float* __restrict__ vchan,
    const float* __restrict__ rsum, float* __restrict__ obuf, int bh0)
{
  const int z = blockIdx.z, bh = bh0 + z, b = bh >> 2, hd = bh & 3;
  const size_t rbase = (size_t)bh * PP;
  const int i0 = blockIdx.y * 128, d0 = blockIdx.x * 64;
  __shared__ ushort pls[128][40];
  __shared__ ushort vls[64][40];
  const int tid = threadIdx.x, lane = tid & 63, wv = tid >> 6;
  const int wi = wv >> 1, wj = wv & 1;
  const int fr = lane & 15, fk = (lane >> 4) * 8, crw = (lane >> 4) * 4;
  const int srow = tid >> 1, scol = (tid & 1) * 16;   // P staging
  const int vdd = tid >> 2, vjj = (tid & 3) * 8;      // V staging
  const size_t vrow = ((size_t)b * CINC + hd * DH + d0 + vdd) * PP;

  const f32x4 zf = {0.f, 0.f, 0.f, 0.f};
  f32x4 acc[4][2];
  #pragma unroll
  for (int rt = 0; rt < 4; ++rt)
    #pragma unroll
    for (int ct = 0; ct < 2; ++ct) acc[rt][ct] = zf;

  for (int k0 = 0; k0 < PPAD; k0 += 32) {
    uint4 pa_ = make_uint4(0,0,0,0), pb_ = pa_;
    {
      int pi = i0 + srow;
      if (pi < PP) {
        const ushort* s = &pbf[((size_t)z * PP + pi) * PPAD + k0 + scol];
        pa_ = *(const uint4*)s; pb_ = *(const uint4*)(s + 8);
      }
    }
    float4 va = make_float4(0.f,0.f,0.f,0.f), vb2 = va;
    if (k0 + vjj < PP) {
      va  = *(const float4*)&vchan[vrow + k0 + vjj];
      vb2 = *(const float4*)&vchan[vrow + k0 + vjj + 4];
    }
    __syncthreads();
    *(uint4*)&pls[srow][scol] = pa_;  *(uint4*)&pls[srow][scol + 8] = pb_;
    {
      uint4 vp;
      vp.x = (unsigned)f2bf(va.x)  | ((unsigned)f2bf(va.y)  << 16);
      vp.y = (unsigned)f2bf(va.z)  | ((unsigned)f2bf(va.w)  << 16);
      vp.z = (unsigned)f2bf(vb2.x) | ((unsigned)f2bf(vb2.y) << 16);
      vp.w = (unsigned)f2bf(vb2.z) | ((unsigned)f2bf(vb2.w) << 16);
      *(uint4*)&vls[vdd][vjj] = vp;
    }
    __syncthreads();
    short8v ap[4], bv[2];
    #pragma unroll
    for (int rt = 0; rt < 4; ++rt)
      ap[rt] = *(const short8v*)&pls[wi * 64 + rt * 16 + fr][fk];
    #pragma unroll
    for (int ct = 0; ct < 2; ++ct)
      bv[ct] = *(const short8v*)&vls[wj * 32 + ct * 16 + fr][fk];
    #pragma unroll
    for (int rt = 0; rt < 4; ++rt)
      #pragma unroll
      for (int ct = 0; ct < 2; ++ct)
        acc[rt][ct] = __builtin_amdgcn_mfma_f32_16x16x32_bf16(
            ap[rt], bv[ct], acc[rt][ct], 0, 0, 0);
  }

  #pragma unroll
  for (int rt = 0; rt < 4; ++rt) {
    const int ib = i0 + wi * 64 + rt * 16 + crw;
    #pragma unroll
    for (int r = 0; r < 4; ++r) {
      const int i = ib + r;
      if (i >= PP) continue;
      const float inv = 1.f / rsum[rbase + i];
      #pragma unroll
      for (int ct = 0; ct < 2; ++ct) {
        const int d = d0 + wj * 32 + ct * 16 + fr;
        obuf[(rbase + i) * DH + d] = acc[rt][ct][r] * inv;
      }
    }
  }
}

// ======================================================================
// K8: output projection + residual (fp32). B gathered from pos-major obuf.
// ======================================================================
__global__ __launch_bounds__(256) void k_out(
    const float* __restrict__ x, const float* __restrict__ obuf,
    const float* __restrict__ wproj, const float* __restrict__ gamma,
    float* __restrict__ out)
{
  const int b = blockIdx.z;
  const int o0 = blockIdx.y * 128, p0 = blockIdx.x * 128;
  __shared__ alignas(16) float als[8 * 132];
  __shared__ alignas(16) float bls[8 * 132];
  const int tid = threadIdx.x;
  const int os4 = (tid & 15) * 4, ps4 = (tid >> 4) * 4;
  float acc[2][2][4][4];
  #pragma unroll
  for (int i = 0; i < 2; ++i)
    #pragma unroll
    for (int j = 0; j < 2; ++j)
      #pragma unroll
      for (int a = 0; a < 4; ++a)
        #pragma unroll
        for (int p = 0; p < 4; ++p) acc[i][j][a][p] = 0.f;

  const int aoo = tid >> 1, add = (tid & 1) * 4;
  const int bpl = tid >> 1, bc4 = (tid & 1) * 4;     // B: 128 p x {0,4} c-offset
  const float* aptr = wproj + (size_t)(o0 + aoo) * CINC + add;

  for (int c0 = 0; c0 < CINC; c0 += 8) {
    float4 av = *(const float4*)(aptr + c0);
    const int hd = c0 / DH, cb = c0 - hd * DH;       // 8 | 192: chunk within one head
    float4 bv = make_float4(0.f, 0.f, 0.f, 0.f);
    {
      int p = p0 + bpl;
      if (p < PP)
        bv = *(const float4*)&obuf[((size_t)(b * NHD + hd) * PP + p) * DH + cb + bc4];
    }
    __syncthreads();
    als[(add + 0) * 132 + aoo] = av.x;
    als[(add + 1) * 132 + aoo] = av.y;
    als[(add + 2) * 132 + aoo] = av.z;
    als[(add + 3) * 132 + aoo] = av.w;
    bls[(bc4 + 0) * 132 + bpl] = bv.x;
    bls[(bc4 + 1) * 132 + bpl] = bv.y;
    bls[(bc4 + 2) * 132 + bpl] = bv.z;
    bls[(bc4 + 3) * 132 + bpl] = bv.w;
    __syncthreads();
    #pragma unroll
    for (int kk = 0; kk < 8; ++kk) {
      const float4 a0 = *(const float4*)&als[kk * 132 + os4];
      const float4 a1 = *(const float4*)&als[kk * 132 + os4 + 64];
      const float4 b0 = *(const float4*)&bls[kk * 132 + ps4];
      const float4 b1 = *(const float4*)&bls[kk * 132 + ps4 + 64];
      FMAQ(acc[0][0], a0, b0) FMAQ(acc[0][1], a0, b1)
      FMAQ(acc[1][0], a1, b0) FMAQ(acc[1][1], a1, b1)
    }
  }
  const float g = gamma[0];
  #pragma unroll
  for (int oq = 0; oq < 2; ++oq)
    #pragma unroll
    for (int a = 0; a < 4; ++a) {
      const int o = o0 + os4 + oq * 64 + a;
      const float* xr = &x[((size_t)b * CINC + o) * PP];
      float* dst = &out[((size_t)b * CINC + o) * PP];
      #pragma unroll
      for (int pq = 0; pq < 2; ++pq) {
        int p = p0 + ps4 + pq * 64;
        if (p < PP) {
          float4 xv = *(const float4*)&xr[p];
          *(float4*)&dst[p] = make_float4(xv.x + g * acc[oq][pq][a][0],
                                          xv.y + g * acc[oq][pq][a][1],
                                          xv.z + g * acc[oq][pq][a][2],
                                          xv.w + g * acc[oq][pq][a][3]);
        }
      }
    }
}

// ======================================================================
extern "C" void kernel_launch(void* const* d_in, const int* in_sizes, int n_in,
                              void* d_out, int out_size, void* d_ws, size_t ws_size,
                              hipStream_t stream)
{
  const float* x    = (const float*)d_in[0];
  const float* w3   = (const float*)d_in[1];
  const float* b3   = (const float*)d_in[2];
  const float* w5   = (const float*)d_in[3];
  const float* b5   = (const float*)d_in[4];
  const float* w7   = (const float*)d_in[5];
  const float* b7   = (const float*)d_in[6];
  const float* wqk  = (const float*)d_in[7];
  const float* relh = (const float*)d_in[8];
  const float* relw = (const float*)d_in[9];
  const float* wv   = (const float*)d_in[10];
  const float* wpr  = (const float*)d_in[11];
  const float* gam  = (const float*)d_in[12];
  float* out = (float*)d_out;
  float* ws  = (float*)d_ws;

  float* conv = ws + OFF_CONV;
  float* qb   = ws + OFF_Q;
  ushort* qbf = (ushort*)(ws + OFF_K);         // bf16 q
  ushort* kbf = qbf + N_QKV;                   // bf16 k
  float* vch  = ws + OFF_V;
  float* obuf = ws + OFF_O;
  float* qrh  = ws + OFF_QRH;
  float* qrw  = ws + OFF_QRW;
  float* rs   = ws + OFF_RS;
  ushort* wbf = (ushort*)(ws + OFF_WT);        // bf16 conv weights
  float* sim  = ws + OFF_SIM;

  // Largest bh-group whose fp32 sim slab + bf16 P slab fit the workspace.
  int g = 8;
  while (g > 1 &&
         (OFF_SIM + (size_t)g * SIM_BH) * sizeof(float) +
         (size_t)g * PP * PPAD * sizeof(ushort) > ws_size) g >>= 1;
  ushort* pbf = (ushort*)(ws + OFF_SIM + (size_t)g * SIM_BH);

  k_wbf<<<dim3(1296, 3), 256, 0, stream>>>(w3, w5, w7, wbf);
  k_conv<<<dim3(31, 2, 6), 256, 0, stream>>>(x, wbf, b3, b5, b7, conv);
  k_qk<<<dim3(16, 12, 2), 256, 0, stream>>>(x, conv, wqk, qb, qbf, kbf);
  k_qrel<<<dim3(NB * NHD * PP), 128, 0, stream>>>(qb, relh, relw, qrh, qrw);
  k_v<<<dim3(16, 6, 2), 256, 0, stream>>>(x, wv, vch);

  for (int bh0 = 0; bh0 < NB * NHD; bh0 += g) {
    k_sim<<<dim3(16, 16, g), 256, 0, stream>>>(qbf, kbf, qrh, qrw, sim, bh0);
    k_softmax<<<dim3(g * PP), 256, 0, stream>>>(sim, pbf, rs, bh0 * PP);
    k_pv<<<dim3(3, 16, g), 256, 0, stream>>>(sim ? pbf : pbf, vch, rs, obuf, bh0);
  }
  k_out<<<dim3(16, 6, 2), 256, 0, stream>>>(x, obuf, wpr, gam, out);
}

// Round 11
// 906.257 us; speedup vs baseline: 5.5106x; 1.6008x over previous
//
#include <hip/hip_runtime.h>
#include <hip/hip_bf16.h>
#include <cstdint>
#include <cstddef>

// ---------------- problem constants ----------------
#define NB   2
#define CINC 768
#define PP   1936          // 44*44
#define CO   384
#define NHD  4
#define DH   192
#define FCH  1920          // 768 + 3*384
#define KCONV 6912         // 768*9
#define PPAD 1952          // PP padded to 61*32 (bf16 P row stride)

typedef __attribute__((ext_vector_type(8))) short short8v;   // 8 bf16
typedef __attribute__((ext_vector_type(4))) float f32x4;     // MFMA acc

__device__ __forceinline__ ushort f2bf(float f) {
  union { float f; unsigned u; } c; c.f = f;
  unsigned b = c.u;
  return (ushort)((b + 0x7FFFu + ((b >> 16) & 1u)) >> 16);   // RNE
}

// ---------------- workspace layout (floats) ----------------
static const size_t OFF_CONV = 0;
static const size_t N_CONV   = (size_t)3 * NB * CO * PP;       // 4,460,544 fp32
static const size_t OFF_Q    = OFF_CONV + N_CONV;
static const size_t N_QKV    = (size_t)NB * NHD * PP * DH;     // 2,973,696
static const size_t OFF_K    = OFF_Q + N_QKV;                  // qbf+kbf bf16
static const size_t OFF_V    = OFF_K + N_QKV;                  // vchan bf16 (N_QKV ushorts)
static const size_t OFF_O    = OFF_V + N_QKV / 2;              // obuf bf16 (N_QKV ushorts)
static const size_t OFF_QRH  = OFF_O + N_QKV / 2;
static const size_t N_QR     = (size_t)NB * NHD * PP * 44;     // 681,472
static const size_t OFF_QRW  = OFF_QRH + N_QR;
static const size_t OFF_RS   = OFF_QRW + N_QR;                 // 15,488 rowsums
static const size_t OFF_WC   = OFF_RS + (size_t)NB * NHD * PP; // conv weights bf16
static const size_t N_WCF    = (size_t)3 * KCONV * CO / 2;     // 3,981,312 floats
static const size_t OFF_WQK  = OFF_WC + N_WCF;                 // wqk bf16
static const size_t N_WQKF   = (size_t)1536 * FCH / 2;         // 1,474,560 floats
static const size_t OFF_WV   = OFF_WQK + N_WQKF;               // wv bf16
static const size_t N_WVF    = (size_t)CINC * CINC / 2;        // 294,912 floats
static const size_t OFF_WP   = OFF_WV + N_WVF;                 // wproj bf16
static const size_t OFF_SIM  = OFF_WP + N_WVF;                 // g*PP*PP fp32 + pbf bf16
static const size_t SIM_BH   = (size_t)PP * PP;                // 3,748,096 per bh

// ======================================================================
// K0a: conv weights fp32 -> bf16 (contiguous copy). grid (1296, 3).
// ======================================================================
__global__ __launch_bounds__(256) void k_wbf(
    const float* __restrict__ w3, const float* __restrict__ w5,
    const float* __restrict__ w7, ushort* __restrict__ wbf)
{
  const int di = blockIdx.y;
  const float* __restrict__ w = (di == 0) ? w3 : (di == 1 ? w5 : w7);
  ushort* __restrict__ dst = wbf + (size_t)di * CO * KCONV;
  const size_t off = ((size_t)blockIdx.x * 256 + threadIdx.x) * 8;
  float4 f0 = *(const float4*)&w[off];
  float4 f1 = *(const float4*)&w[off + 4];
  uint4 pk;
  pk.x = (unsigned)f2bf(f0.x) | ((unsigned)f2bf(f0.y) << 16);
  pk.y = (unsigned)f2bf(f0.z) | ((unsigned)f2bf(f0.w) << 16);
  pk.z = (unsigned)f2bf(f1.x) | ((unsigned)f2bf(f1.y) << 16);
  pk.w = (unsigned)f2bf(f1.z) | ((unsigned)f2bf(f1.w) << 16);
  *(uint4*)&dst[off] = pk;
}

// ======================================================================
// K0b: generic fp32 -> bf16 copy, 2048 elems/block.
// ======================================================================
__global__ __launch_bounds__(256) void k_cvt(
    const float* __restrict__ src, ushort* __restrict__ dst)
{
  const size_t off = ((size_t)blockIdx.x * 256 + threadIdx.x) * 8;
  float4 f0 = *(const float4*)&src[off];
  float4 f1 = *(const float4*)&src[off + 4];
  uint4 pk;
  pk.x = (unsigned)f2bf(f0.x) | ((unsigned)f2bf(f0.y) << 16);
  pk.y = (unsigned)f2bf(f0.z) | ((unsigned)f2bf(f0.w) << 16);
  pk.z = (unsigned)f2bf(f1.x) | ((unsigned)f2bf(f1.y) << 16);
  pk.w = (unsigned)f2bf(f1.z) | ((unsigned)f2bf(f1.w) << 16);
  *(uint4*)&dst[off] = pk;
}

// ======================================================================
// K1: dilated convs as implicit-GEMM MFMA (unchanged from r9).
// Block 192co x 64pos, 4 waves (2x2), acc[6][2]. grid (31, 2, 6).
// ======================================================================
__global__ __launch_bounds__(256) void k_conv(
    const float* __restrict__ x, const ushort* __restrict__ wbf,
    const float* __restrict__ b3, const float* __restrict__ b5,
    const float* __restrict__ b7, float* __restrict__ conv_out)
{
  __shared__ ushort als[192][40];
  __shared__ ushort bls[64][40];
  const int z = blockIdx.z, di = z >> 1, b = z & 1;
  const int dil = 3 + 2 * di;
  const ushort* __restrict__ wd = wbf + (size_t)di * CO * KCONV;
  const float* __restrict__ bia = (di == 0) ? b3 : (di == 1 ? b5 : b7);
  const float* __restrict__ xb = x + (size_t)b * CINC * PP;
  const int p0 = blockIdx.x * 64;
  const int co0 = blockIdx.y * 192;
  const int tid = threadIdx.x, lane = tid & 63, wv = tid >> 6;
  const int wi = wv >> 1, wj = wv & 1;
  const int fr = lane & 15, fk = (lane >> 4) * 8, crw = (lane >> 4) * 4;

  const int aco = tid >> 2, akf = (tid & 3) * 8;
  const int bpos_l = tid >> 2, bkk0 = (tid & 3) * 8;
  const int bpos = p0 + bpos_l;
  const unsigned ypos = (unsigned)bpos / 44u;
  const unsigned xpos = (unsigned)bpos - 44u * ypos;
  const bool bvalid = bpos < PP;

  const f32x4 zf = {0.f, 0.f, 0.f, 0.f};
  f32x4 acc[6][2];
  #pragma unroll
  for (int rt = 0; rt < 6; ++rt)
    #pragma unroll
    for (int ct = 0; ct < 2; ++ct) acc[rt][ct] = zf;

  for (int k0 = 0; k0 < KCONV; k0 += 32) {
    ushort tmp[8];
    #pragma unroll
    for (int i = 0; i < 8; ++i) {
      const int k = k0 + bkk0 + i;
      const unsigned ci = (unsigned)k / 9u;
      const unsigned tap = (unsigned)k - 9u * ci;
      const unsigned kh = tap / 3u;
      const unsigned kw = tap - 3u * kh;
      const int gy = (int)ypos + dil * (int)kh - dil;
      const int gx = (int)xpos + dil * (int)kw - dil;
      float v = 0.f;
      if (bvalid && (unsigned)gy < 44u && (unsigned)gx < 44u)
        v = xb[(size_t)ci * PP + gy * 44 + gx];
      tmp[i] = f2bf(v);
    }
    __syncthreads();
    #pragma unroll
    for (int r = 0; r < 3; ++r) {
      const int co = r * 64 + aco;
      *(uint4*)&als[co][akf] =
          *(const uint4*)&wd[(size_t)(co0 + co) * KCONV + k0 + akf];
    }
    {
      uint4 pk;
      pk.x = (unsigned)tmp[0] | ((unsigned)tmp[1] << 16);
      pk.y = (unsigned)tmp[2] | ((unsigned)tmp[3] << 16);
      pk.z = (unsigned)tmp[4] | ((unsigned)tmp[5] << 16);
      pk.w = (unsigned)tmp[6] | ((unsigned)tmp[7] << 16);
      *(uint4*)&bls[bpos_l][bkk0] = pk;
    }
    __syncthreads();
    short8v af[6], bf_[2];
    #pragma unroll
    for (int rt = 0; rt < 6; ++rt)
      af[rt] = *(const short8v*)&als[wi * 96 + rt * 16 + fr][fk];
    #pragma unroll
    for (int ct = 0; ct < 2; ++ct)
      bf_[ct] = *(const short8v*)&bls[wj * 32 + ct * 16 + fr][fk];
    #pragma unroll
    for (int rt = 0; rt < 6; ++rt)
      #pragma unroll
      for (int ct = 0; ct < 2; ++ct)
        acc[rt][ct] = __builtin_amdgcn_mfma_f32_16x16x32_bf16(
            af[rt], bf_[ct], acc[rt][ct], 0, 0, 0);
  }

  float* __restrict__ outb = conv_out + (size_t)(di * NB + b) * CO * PP;
  #pragma unroll
  for (int rt = 0; rt < 6; ++rt) {
    #pragma unroll
    for (int r = 0; r < 4; ++r) {
      const int co = co0 + wi * 96 + rt * 16 + crw + r;
      const float bv = bia[co];
      #pragma unroll
      for (int ct = 0; ct < 2; ++ct) {
        const int pos = p0 + wj * 32 + ct * 16 + fr;
        if (pos < PP) outb[(size_t)co * PP + pos] = acc[rt][ct][r] + bv;
      }
    }
  }
}

// ======================================================================
// K2 v3: qk projection as MFMA. A = wqk bf16 [1536][1920], B staged
// transposed from fp32 x/conv (8 pos-contiguous loads -> 8 scalar LDS
// writes). Block 192o x 64p, grid (31, 8, 2).
// ======================================================================
__global__ __launch_bounds__(256) void k_qk(
    const float* __restrict__ x, const float* __restrict__ conv,
    const ushort* __restrict__ wqkb,
    float* __restrict__ qbuf, ushort* __restrict__ qbf, ushort* __restrict__ kbf)
{
  __shared__ ushort als[192][40];
  __shared__ ushort bls[64][40];
  const int b = blockIdx.z;
  const int o0 = blockIdx.y * 192, p0 = blockIdx.x * 64;
  const int tid = threadIdx.x, lane = tid & 63, wv = tid >> 6;
  const int wi = wv >> 1, wj = wv & 1;
  const int fr = lane & 15, fk = (lane >> 4) * 8, crw = (lane >> 4) * 4;
  const int aco = tid >> 2, akf = (tid & 3) * 8;
  const int bc = tid & 31;               // channel within chunk
  const int bp8 = (tid >> 5) * 8;        // 8-pos sub-block
  const bool ptail = (p0 + 64 > PP);

  const f32x4 zf = {0.f, 0.f, 0.f, 0.f};
  f32x4 acc[6][2];
  #pragma unroll
  for (int rt = 0; rt < 6; ++rt)
    #pragma unroll
    for (int ct = 0; ct < 2; ++ct) acc[rt][ct] = zf;

  for (int k0 = 0; k0 < FCH; k0 += 32) {
    float bvv[8];
    {
      const int c = k0 + bc;
      const float* src;
      if (c < CINC) src = x + ((size_t)b * CINC + c) * PP;
      else {
        const int c2 = c - CINC;
        const int dd2 = c2 / CO, cc2 = c2 - dd2 * CO;
        src = conv + ((size_t)(dd2 * NB + b) * CO + cc2) * PP;
      }
      const int pbase = p0 + bp8;
      if (!ptail) {
        float4 u0 = *(const float4*)&src[pbase];
        float4 u1 = *(const float4*)&src[pbase + 4];
        bvv[0]=u0.x; bvv[1]=u0.y; bvv[2]=u0.z; bvv[3]=u0.w;
        bvv[4]=u1.x; bvv[5]=u1.y; bvv[6]=u1.z; bvv[7]=u1.w;
      } else {
        #pragma unroll
        for (int i = 0; i < 8; ++i)
          bvv[i] = (pbase + i < PP) ? src[pbase + i] : 0.f;
      }
    }
    __syncthreads();
    #pragma unroll
    for (int r = 0; r < 3; ++r) {
      const int co = r * 64 + aco;
      *(uint4*)&als[co][akf] =
          *(const uint4*)&wqkb[(size_t)(o0 + co) * FCH + k0 + akf];
    }
    #pragma unroll
    for (int i = 0; i < 8; ++i) bls[bp8 + i][bc] = f2bf(bvv[i]);
    __syncthreads();
    short8v af[6], bf_[2];
    #pragma unroll
    for (int rt = 0; rt < 6; ++rt)
      af[rt] = *(const short8v*)&als[wi * 96 + rt * 16 + fr][fk];
    #pragma unroll
    for (int ct = 0; ct < 2; ++ct)
      bf_[ct] = *(const short8v*)&bls[wj * 32 + ct * 16 + fr][fk];
    #pragma unroll
    for (int rt = 0; rt < 6; ++rt)
      #pragma unroll
      for (int ct = 0; ct < 2; ++ct)
        acc[rt][ct] = __builtin_amdgcn_mfma_f32_16x16x32_bf16(
            af[rt], bf_[ct], acc[rt][ct], 0, 0, 0);
  }

  #pragma unroll
  for (int rt = 0; rt < 6; ++rt) {
    #pragma unroll
    for (int r = 0; r < 4; ++r) {
      const int o = o0 + wi * 96 + rt * 16 + crw + r;
      const bool isq = (o < CINC);
      const int oo = isq ? o : o - CINC;
      const int hd = oo / DH, dd = oo - hd * DH;
      const size_t rowb = (size_t)(b * NHD + hd) * PP;
      const float s = isq ? 0.5f : 1.0f;   // HEAD^-0.5 = 0.5
      #pragma unroll
      for (int ct = 0; ct < 2; ++ct) {
        const int pos = p0 + wj * 32 + ct * 16 + fr;
        if (pos >= PP) continue;
        const float fv = acc[rt][ct][r] * s;
        if (isq) {
          qbuf[(rowb + pos) * DH + dd] = fv;
          qbf [(rowb + pos) * DH + dd] = f2bf(fv);
        } else {
          kbf [(rowb + pos) * DH + dd] = f2bf(fv);
        }
      }
    }
  }
}

// ======================================================================
// K3: rel-pos dot products (fp32 q) — unchanged.
// ======================================================================
__global__ __launch_bounds__(128) void k_qrel(
    const float* __restrict__ qbuf, const float* __restrict__ relh,
    const float* __restrict__ relw,
    float* __restrict__ qrh, float* __restrict__ qrw)
{
  const int bh = blockIdx.x / PP, pos = blockIdx.x % PP;
  const int xr = pos / 44, yc = pos - 44 * xr;
  __shared__ alignas(16) float qs[192];
  const int tid = threadIdx.x;
  for (int e = tid; e < 192; e += 128)
    qs[e] = qbuf[((size_t)bh * PP + pos) * DH + e];
  __syncthreads();
  const float4* q4 = (const float4*)qs;
  if (tid < 44) {
    const float4* r4 = (const float4*)&relh[(size_t)(tid - xr + 99) * DH];
    float s = 0.f;
    #pragma unroll
    for (int d = 0; d < 48; ++d) {
      float4 a = q4[d], bb = r4[d];
      s += a.x * bb.x + a.y * bb.y + a.z * bb.z + a.w * bb.w;
    }
    qrh[((size_t)bh * PP + pos) * 44 + tid] = s;
  } else if (tid >= 64 && tid < 108) {
    const int v = tid - 64;
    const float4* r4 = (const float4*)&relw[(size_t)(v - yc + 99) * DH];
    float s = 0.f;
    #pragma unroll
    for (int d = 0; d < 48; ++d) {
      float4 a = q4[d], bb = r4[d];
      s += a.x * bb.x + a.y * bb.y + a.z * bb.z + a.w * bb.w;
    }
    qrw[((size_t)bh * PP + pos) * 44 + v] = s;
  }
}

// ======================================================================
// K4 v2: v projection as MFMA -> bf16 channel-major vchan.
// A = wv bf16 [768][768], B transposed-staged from x. grid (31, 4, 2).
// ======================================================================
__global__ __launch_bounds__(256) void k_v(
    const float* __restrict__ x, const ushort* __restrict__ wvb,
    ushort* __restrict__ vcb)
{
  __shared__ ushort als[192][40];
  __shared__ ushort bls[64][40];
  const int b = blockIdx.z;
  const int o0 = blockIdx.y * 192, p0 = blockIdx.x * 64;
  const int tid = threadIdx.x, lane = tid & 63, wv = tid >> 6;
  const int wi = wv >> 1, wj = wv & 1;
  const int fr = lane & 15, fk = (lane >> 4) * 8, crw = (lane >> 4) * 4;
  const int aco = tid >> 2, akf = (tid & 3) * 8;
  const int bc = tid & 31, bp8 = (tid >> 5) * 8;
  const bool ptail = (p0 + 64 > PP);

  const f32x4 zf = {0.f, 0.f, 0.f, 0.f};
  f32x4 acc[6][2];
  #pragma unroll
  for (int rt = 0; rt < 6; ++rt)
    #pragma unroll
    for (int ct = 0; ct < 2; ++ct) acc[rt][ct] = zf;

  for (int k0 = 0; k0 < CINC; k0 += 32) {
    float bvv[8];
    {
      const float* src = x + ((size_t)b * CINC + k0 + bc) * PP;
      const int pbase = p0 + bp8;
      if (!ptail) {
        float4 u0 = *(const float4*)&src[pbase];
        float4 u1 = *(const float4*)&src[pbase + 4];
        bvv[0]=u0.x; bvv[1]=u0.y; bvv[2]=u0.z; bvv[3]=u0.w;
        bvv[4]=u1.x; bvv[5]=u1.y; bvv[6]=u1.z; bvv[7]=u1.w;
      } else {
        #pragma unroll
        for (int i = 0; i < 8; ++i)
          bvv[i] = (pbase + i < PP) ? src[pbase + i] : 0.f;
      }
    }
    __syncthreads();
    #pragma unroll
    for (int r = 0; r < 3; ++r) {
      const int co = r * 64 + aco;
      *(uint4*)&als[co][akf] =
          *(const uint4*)&wvb[(size_t)(o0 + co) * CINC + k0 + akf];
    }
    #pragma unroll
    for (int i = 0; i < 8; ++i) bls[bp8 + i][bc] = f2bf(bvv[i]);
    __syncthreads();
    short8v af[6], bf_[2];
    #pragma unroll
    for (int rt = 0; rt < 6; ++rt)
      af[rt] = *(const short8v*)&als[wi * 96 + rt * 16 + fr][fk];
    #pragma unroll
    for (int ct = 0; ct < 2; ++ct)
      bf_[ct] = *(const short8v*)&bls[wj * 32 + ct * 16 + fr][fk];
    #pragma unroll
    for (int rt = 0; rt < 6; ++rt)
      #pragma unroll
      for (int ct = 0; ct < 2; ++ct)
        acc[rt][ct] = __builtin_amdgcn_mfma_f32_16x16x32_bf16(
            af[rt], bf_[ct], acc[rt][ct], 0, 0, 0);
  }

  #pragma unroll
  for (int rt = 0; rt < 6; ++rt) {
    #pragma unroll
    for (int r = 0; r < 4; ++r) {
      const int o = o0 + wi * 96 + rt * 16 + crw + r;
      ushort* row = vcb + ((size_t)b * CINC + o) * PP;
      #pragma unroll
      for (int ct = 0; ct < 2; ++ct) {
        const int pos = p0 + wj * 32 + ct * 16 + fr;
        if (pos < PP) row[pos] = f2bf(acc[rt][ct][r]);
      }
    }
  }
}

// ======================================================================
// K5: MFMA QK^T — unchanged.
// ======================================================================
__global__ __launch_bounds__(256) void k_sim(
    const ushort* __restrict__ qbf, const ushort* __restrict__ kbf,
    const float* __restrict__ qrh, const float* __restrict__ qrw,
    float* __restrict__ sim, int bh0)
{
  const int z = blockIdx.z, bh = bh0 + z;
  const size_t base = (size_t)bh * PP;
  const size_t sbase = (size_t)z * PP;
  const int i0 = blockIdx.y * 128, j0 = blockIdx.x * 128;
  __shared__ ushort qls[128][40];
  __shared__ ushort kls[128][40];
  const int tid = threadIdx.x, lane = tid & 63, wv = tid >> 6;
  const int wi = wv >> 1, wj = wv & 1;
  const int fr = lane & 15, fk = (lane >> 4) * 8, crw = (lane >> 4) * 4;
  const int srow = tid >> 1, scol = (tid & 1) * 16;

  const f32x4 zf = {0.f, 0.f, 0.f, 0.f};
  f32x4 acc[4][4];
  #pragma unroll
  for (int rt = 0; rt < 4; ++rt)
    #pragma unroll
    for (int ct = 0; ct < 4; ++ct) acc[rt][ct] = zf;

  for (int d0 = 0; d0 < DH; d0 += 32) {
    uint4 qa = make_uint4(0,0,0,0), qb = qa, ka = qa, kb2 = qa;
    {
      int qi = i0 + srow;
      if (qi < PP) {
        const ushort* s = &qbf[(base + qi) * DH + d0 + scol];
        qa = *(const uint4*)s; qb = *(const uint4*)(s + 8);
      }
      int kj = j0 + srow;
      if (kj < PP) {
        const ushort* s = &kbf[(base + kj) * DH + d0 + scol];
        ka = *(const uint4*)s; kb2 = *(const uint4*)(s + 8);
      }
    }
    __syncthreads();
    *(uint4*)&qls[srow][scol] = qa;  *(uint4*)&qls[srow][scol + 8] = qb;
    *(uint4*)&kls[srow][scol] = ka;  *(uint4*)&kls[srow][scol + 8] = kb2;
    __syncthreads();
    short8v aq[4], bk[4];
    #pragma unroll
    for (int rt = 0; rt < 4; ++rt)
      aq[rt] = *(const short8v*)&qls[wi * 64 + rt * 16 + fr][fk];
    #pragma unroll
    for (int ct = 0; ct < 4; ++ct)
      bk[ct] = *(const short8v*)&kls[wj * 64 + ct * 16 + fr][fk];
    #pragma unroll
    for (int rt = 0; rt < 4; ++rt)
      #pragma unroll
      for (int ct = 0; ct < 4; ++ct)
        acc[rt][ct] = __builtin_amdgcn_mfma_f32_16x16x32_bf16(
            aq[rt], bk[ct], acc[rt][ct], 0, 0, 0);
  }

  #pragma unroll
  for (int ct = 0; ct < 4; ++ct) {
    const int j = j0 + wj * 64 + ct * 16 + fr;
    if (j >= PP) continue;
    const int u = j / 44, v = j - 44 * u;
    #pragma unroll
    for (int rt = 0; rt < 4; ++rt) {
      const int ib = i0 + wi * 64 + rt * 16 + crw;
      #pragma unroll
      for (int r = 0; r < 4; ++r) {
        const int i = ib + r;
        if (i < PP)
          sim[(sbase + i) * PP + j] =
              acc[rt][ct][r] + qrh[(base + i) * 44 + u] + qrw[(base + i) * 44 + v];
      }
    }
  }
}

// ======================================================================
// K6: row softmax — unchanged.
// ======================================================================
__global__ __launch_bounds__(256) void k_softmax(
    float* __restrict__ sim, ushort* __restrict__ pbf,
    float* __restrict__ rsum, int row0)
{
  const size_t row = blockIdx.x;
  float4* p = (float4*)(sim + row * PP);
  ushort* pb = pbf + row * PPAD;
  const int tid = threadIdx.x;
  __shared__ float sred[4];

  float4 v0 = p[tid];
  float mx = fmaxf(fmaxf(v0.x, v0.y), fmaxf(v0.z, v0.w));
  const bool has2 = (tid + 256) < 484;
  float4 v1 = make_float4(0.f, 0.f, 0.f, 0.f);
  if (has2) {
    v1 = p[tid + 256];
    mx = fmaxf(mx, fmaxf(fmaxf(v1.x, v1.y), fmaxf(v1.z, v1.w)));
  }
  #pragma unroll
  for (int o = 32; o; o >>= 1) mx = fmaxf(mx, __shfl_xor(mx, o));
  if ((tid & 63) == 0) sred[tid >> 6] = mx;
  __syncthreads();
  mx = fmaxf(fmaxf(sred[0], sred[1]), fmaxf(sred[2], sred[3]));

  float sum;
  v0.x = __expf(v0.x - mx); v0.y = __expf(v0.y - mx);
  v0.z = __expf(v0.z - mx); v0.w = __expf(v0.w - mx);
  sum = v0.x + v0.y + v0.z + v0.w;
  p[tid] = v0;
  {
    unsigned lo = (unsigned)f2bf(v0.x) | ((unsigned)f2bf(v0.y) << 16);
    unsigned hi = (unsigned)f2bf(v0.z) | ((unsigned)f2bf(v0.w) << 16);
    *(uint2*)&pb[tid * 4] = make_uint2(lo, hi);
  }
  if (has2) {
    v1.x = __expf(v1.x - mx); v1.y = __expf(v1.y - mx);
    v1.z = __expf(v1.z - mx); v1.w = __expf(v1.w - mx);
    sum += v1.x + v1.y + v1.z + v1.w;
    p[tid + 256] = v1;
    unsigned lo = (unsigned)f2bf(v1.x) | ((unsigned)f2bf(v1.y) << 16);
    unsigned hi = (unsigned)f2bf(v1.z) | ((unsigned)f2bf(v1.w) << 16);
    *(uint2*)&pb[(tid + 256) * 4] = make_uint2(lo, hi);
  }
  if (tid < 2) *(uint4*)&pb[1936 + tid * 8] = make_uint4(0, 0, 0, 0);
  #pragma unroll
  for (int o = 32; o; o >>= 1) sum += __shfl_xor(sum, o);
  __syncthreads();
  if ((tid & 63) == 0) sred[tid >> 6] = sum;
  __syncthreads();
  if (tid == 0) rsum[row0 + row] = sred[0] + sred[1] + sred[2] + sred[3];
}

// ======================================================================
// K7 v2: MFMA PV. vchan now bf16 (uint4 staging, no cvt); obuf bf16 out.
// ======================================================================
__global__ __launch_bounds__(256) void k_pv(
    const ushort* __restrict__ pbf, const ushort* __restrict__ vcb,
    const float* __restrict__ rsum, ushort* __restrict__ obf, int bh0)
{
  const int z = blockIdx.z, bh = bh0 + z, b = bh >> 2, hd = bh & 3;
  const size_t rbase = (size_t)bh * PP;
  const int i0 = blockIdx.y * 128, d0 = blockIdx.x * 64;
  __shared__ ushort pls[128][40];
  __shared__ ushort vls[64][40];
  const int tid = threadIdx.x, lane = tid & 63, wv = tid >> 6;
  const int wi = wv >> 1, wj = wv & 1;
  const int fr = lane & 15, fk = (lane >> 4) * 8, crw = (lane >> 4) * 4;
  const int srow = tid >> 1, scol = (tid & 1) * 16;   // P staging
  const int vdd = tid >> 2, vjj = (tid & 3) * 8;      // V staging
  const size_t vrow = ((size_t)b * CINC + hd * DH + d0 + vdd) * PP;

  const f32x4 zf = {0.f, 0.f, 0.f, 0.f};
  f32x4 acc[4][2];
  #pragma unroll
  for (int rt = 0; rt < 4; ++rt)
    #pragma unroll
    for (int ct = 0; ct < 2; ++ct) acc[rt][ct] = zf;

  for (int k0 = 0; k0 < PPAD; k0 += 32) {
    uint4 pa_ = make_uint4(0,0,0,0), pb_ = pa_;
    {
      int pi = i0 + srow;
      if (pi < PP) {
        const ushort* s = &pbf[((size_t)z * PP + pi) * PPAD + k0 + scol];
        pa_ = *(const uint4*)s; pb_ = *(const uint4*)(s + 8);
      }
    }
    uint4 vp = make_uint4(0,0,0,0);
    if (k0 + vjj < PP) vp = *(const uint4*)&vcb[vrow + k0 + vjj];
    __syncthreads();
    *(uint4*)&pls[srow][scol] = pa_;  *(uint4*)&pls[srow][scol + 8] = pb_;
    *(uint4*)&vls[vdd][vjj] = vp;
    __syncthreads();
    short8v ap[4], bv[2];
    #pragma unroll
    for (int rt = 0; rt < 4; ++rt)
      ap[rt] = *(const short8v*)&pls[wi * 64 + rt * 16 + fr][fk];
    #pragma unroll
    for (int ct = 0; ct < 2; ++ct)
      bv[ct] = *(const short8v*)&vls[wj * 32 + ct * 16 + fr][fk];
    #pragma unroll
    for (int rt = 0; rt < 4; ++rt)
      #pragma unroll
      for (int ct = 0; ct < 2; ++ct)
        acc[rt][ct] = __builtin_amdgcn_mfma_f32_16x16x32_bf16(
            ap[rt], bv[ct], acc[rt][ct], 0, 0, 0);
  }

  #pragma unroll
  for (int rt = 0; rt < 4; ++rt) {
    const int ib = i0 + wi * 64 + rt * 16 + crw;
    #pragma unroll
    for (int r = 0; r < 4; ++r) {
      const int i = ib + r;
      if (i >= PP) continue;
      const float inv = 1.f / rsum[rbase + i];
      #pragma unroll
      for (int ct = 0; ct < 2; ++ct) {
        const int d = d0 + wj * 32 + ct * 16 + fr;
        obf[(rbase + i) * DH + d] = f2bf(acc[rt][ct][r] * inv);
      }
    }
  }
}

// ======================================================================
// K8 v2: output projection as MFMA + residual.
// A = wproj bf16 [768][768], B = obuf bf16 pos-major (uint4 staging).
// grid (31, 4, 2).
// ======================================================================
__global__ __launch_bounds__(256) void k_out(
    const float* __restrict__ x, const ushort* __restrict__ obf,
    const ushort* __restrict__ wpb, const float* __restrict__ gamma,
    float* __restrict__ out)
{
  __shared__ ushort als[192][40];
  __shared__ ushort bls[64][40];
  const int b = blockIdx.z;
  const int o0 = blockIdx.y * 192, p0 = blockIdx.x * 64;
  const int tid = threadIdx.x, lane = tid & 63, wv = tid >> 6;
  const int wi = wv >> 1, wj = wv & 1;
  const int fr = lane & 15, fk = (lane >> 4) * 8, crw = (lane >> 4) * 4;
  const int aco = tid >> 2, akf = (tid & 3) * 8;
  const int bpl = tid >> 2, bk8 = (tid & 3) * 8;

  const f32x4 zf = {0.f, 0.f, 0.f, 0.f};
  f32x4 acc[6][2];
  #pragma unroll
  for (int rt = 0; rt < 6; ++rt)
    #pragma unroll
    for (int ct = 0; ct < 2; ++ct) acc[rt][ct] = zf;

  for (int k0 = 0; k0 < CINC; k0 += 32) {
    const int hd = k0 / DH, cb = k0 - hd * DH;    // chunk stays in one head
    uint4 bv = make_uint4(0,0,0,0);
    {
      const int p = p0 + bpl;
      if (p < PP)
        bv = *(const uint4*)&obf[((size_t)(b * NHD + hd) * PP + p) * DH + cb + bk8];
    }
    __syncthreads();
    #pragma unroll
    for (int r = 0; r < 3; ++r) {
      const int co = r * 64 + aco;
      *(uint4*)&als[co][akf] =
          *(const uint4*)&wpb[(size_t)(o0 + co) * CINC + k0 + akf];
    }
    *(uint4*)&bls[bpl][bk8] = bv;
    __syncthreads();
    short8v af[6], bf_[2];
    #pragma unroll
    for (int rt = 0; rt < 6; ++rt)
      af[rt] = *(const short8v*)&als[wi * 96 + rt * 16 + fr][fk];
    #pragma unroll
    for (int ct = 0; ct < 2; ++ct)
      bf_[ct] = *(const short8v*)&bls[wj * 32 + ct * 16 + fr][fk];
    #pragma unroll
    for (int rt = 0; rt < 6; ++rt)
      #pragma unroll
      for (int ct = 0; ct < 2; ++ct)
        acc[rt][ct] = __builtin_amdgcn_mfma_f32_16x16x32_bf16(
            af[rt], bf_[ct], acc[rt][ct], 0, 0, 0);
  }

  const float g = gamma[0];
  #pragma unroll
  for (int rt = 0; rt < 6; ++rt) {
    #pragma unroll
    for (int r = 0; r < 4; ++r) {
      const int o = o0 + wi * 96 + rt * 16 + crw + r;
      const float* xr = &x[((size_t)b * CINC + o) * PP];
      float* dst = &out[((size_t)b * CINC + o) * PP];
      #pragma unroll
      for (int ct = 0; ct < 2; ++ct) {
        const int pos = p0 + wj * 32 + ct * 16 + fr;
        if (pos < PP) dst[pos] = xr[pos] + g * acc[rt][ct][r];
      }
    }
  }
}

// ======================================================================
extern "C" void kernel_launch(void* const* d_in, const int* in_sizes, int n_in,
                              void* d_out, int out_size, void* d_ws, size_t ws_size,
                              hipStream_t stream)
{
  const float* x    = (const float*)d_in[0];
  const float* w3   = (const float*)d_in[1];
  const float* b3   = (const float*)d_in[2];
  const float* w5   = (const float*)d_in[3];
  const float* b5   = (const float*)d_in[4];
  const float* w7   = (const float*)d_in[5];
  const float* b7   = (const float*)d_in[6];
  const float* wqk  = (const float*)d_in[7];
  const float* relh = (const float*)d_in[8];
  const float* relw = (const float*)d_in[9];
  const float* wvw  = (const float*)d_in[10];
  const float* wpr  = (const float*)d_in[11];
  const float* gam  = (const float*)d_in[12];
  float* out = (float*)d_out;
  float* ws  = (float*)d_ws;

  float*  conv = ws + OFF_CONV;
  float*  qb   = ws + OFF_Q;
  ushort* qbf  = (ushort*)(ws + OFF_K);
  ushort* kbf  = qbf + N_QKV;
  ushort* vcb  = (ushort*)(ws + OFF_V);
  ushort* obf  = (ushort*)(ws + OFF_O);
  float*  qrh  = ws + OFF_QRH;
  float*  qrw  = ws + OFF_QRW;
  float*  rs   = ws + OFF_RS;
  ushort* wcb  = (ushort*)(ws + OFF_WC);
  ushort* wqkb = (ushort*)(ws + OFF_WQK);
  ushort* wvb  = (ushort*)(ws + OFF_WV);
  ushort* wpb  = (ushort*)(ws + OFF_WP);
  float*  sim  = ws + OFF_SIM;

  // Largest bh-group whose fp32 sim slab + bf16 P slab fit the workspace.
  int g = 8;
  while (g > 1 &&
         (OFF_SIM + (size_t)g * SIM_BH) * sizeof(float) +
         (size_t)g * PP * PPAD * sizeof(ushort) > ws_size) g >>= 1;
  ushort* pbf = (ushort*)(ws + OFF_SIM + (size_t)g * SIM_BH);

  k_wbf<<<dim3(1296, 3), 256, 0, stream>>>(w3, w5, w7, wcb);
  k_cvt<<<dim3(1440), 256, 0, stream>>>(wqk, wqkb);
  k_cvt<<<dim3(288), 256, 0, stream>>>(wvw, wvb);
  k_cvt<<<dim3(288), 256, 0, stream>>>(wpr, wpb);
  k_conv<<<dim3(31, 2, 6), 256, 0, stream>>>(x, wcb, b3, b5, b7, conv);
  k_qk<<<dim3(31, 8, 2), 256, 0, stream>>>(x, conv, wqkb, qb, qbf, kbf);
  k_qrel<<<dim3(NB * NHD * PP), 128, 0, stream>>>(qb, relh, relw, qrh, qrw);
  k_v<<<dim3(31, 4, 2), 256, 0, stream>>>(x, wvb, vcb);

  for (int bh0 = 0; bh0 < NB * NHD; bh0 += g) {
    k_sim<<<dim3(16, 16, g), 256, 0, stream>>>(qbf, kbf, qrh, qrw, sim, bh0);
    k_softmax<<<dim3(g * PP), 256, 0, stream>>>(sim, pbf, rs, bh0 * PP);
    k_pv<<<dim3(3, 16, g), 256, 0, stream>>>(pbf, vcb, rs, obf, bh0);
  }
  k_out<<<dim3(31, 4, 2), 256, 0, stream>>>(x, obf, wpb, gam, out);
}